// Round 10
// baseline (1157.361 us; speedup 1.0000x reference)
//
#include <hip/hip_runtime.h>
#include <math.h>

#define T_TOK 2048
#define NE 64
#define KTOP 8
#define CAPC 512
#define DIN 768
#define HD 2048
#define BTD 256
#define OD 768

typedef short bf16x8 __attribute__((ext_vector_type(8)));
typedef float f32x4 __attribute__((ext_vector_type(4)));

__device__ __forceinline__ unsigned short f2bf(float f) {
  unsigned u = __float_as_uint(f);
  u += 0x7FFF + ((u >> 16) & 1);   // round-to-nearest-even
  return (unsigned short)(u >> 16);
}
__device__ __forceinline__ unsigned cvt2(float a, float b) {
  unsigned r;
  asm("v_cvt_pk_bf16_f32 %0, %1, %2" : "=v"(r) : "v"(a), "v"(b));
  return r;   // lo = bf16(a), hi = bf16(b)
}
__device__ __forceinline__ float gelu_exact(float v) {
  return 0.5f * v * (1.0f + erff(v * 0.7071067811865476f));
}
__device__ __forceinline__ void glds16(unsigned short* lds, const unsigned short* g) {
  __builtin_amdgcn_global_load_lds(
      (const __attribute__((address_space(1))) void*)g,
      (__attribute__((address_space(3))) void*)lds, 16, 0, 0);
}

// ---------------- x fp32 -> bf16 ---------------------------------------------------
__global__ __launch_bounds__(256) void cvt_x(const float* __restrict__ x,
                                             unsigned short* __restrict__ xb) {
  int i = blockIdx.x * 256 + threadIdx.x;
  float4 v = ((const float4*)x)[i];
  ushort4 o;
  o.x = f2bf(v.x); o.y = f2bf(v.y); o.z = f2bf(v.z); o.w = f2bf(v.w);
  ((ushort4*)xb)[i] = o;
}

// ---------------- retile v3: dense reads AND dense writes --------------------------
// Tile (e,p,t) = 4096 shorts, q-major: section q (1024 shorts = 2KB contiguous) holds
// k-rows 32t+8q..+7; position q*1024 + j*8 + h = bf16 W[32t+8q+h][128p + ((j-q)&127)].
// Block = 8 k-rows (one q of one t) x full ND: reads 8 FULL rows (dense 64KB max),
// writes complete 2KB contiguous chunks (one per panel). Both sides dense streams.
template<int KD, int ND>
__global__ __launch_bounds__(256) void retile3(const float* __restrict__ W,
                                               unsigned short* __restrict__ Bt) {
  constexpr int KT = KD / 32;
  constexpr int NP = ND / 128;
  const int rg = blockIdx.x;          // 0 .. KD/8-1
  const int e  = blockIdx.y;
  const int t = rg >> 2, q = rg & 3;
  const int tid = threadIdx.x;
  __shared__ float L[8 * ND];
  const float* src = W + ((size_t)e * KD + 32 * t + 8 * q) * ND;
  #pragma unroll 4
  for (int i = tid; i < 8 * ND / 4; i += 256) ((float4*)L)[i] = ((const float4*)src)[i];
  __syncthreads();
  unsigned short* oute = Bt + (size_t)e * NP * KT * 4096 + (size_t)t * 4096 + q * 1024;
  for (int idx = tid; idx < ND; idx += 256) {
    int p = idx >> 7, j = idx & 127;
    int col = 128 * p + ((j - q) & 127);
    union { bf16x8 v; unsigned u[4]; } pk;
    #pragma unroll
    for (int h = 0; h < 4; h++)
      pk.u[h] = cvt2(L[(2 * h) * ND + col], L[(2 * h + 1) * ND + col]);
    *(bf16x8*)&oute[(size_t)p * KT * 4096 + j * 8] = pk.v;
  }
}

// ---------------- router: fp32 logits, noisy top-8, softmax, gate/slot matrices ----
__global__ __launch_bounds__(256) void router_kernel(
    const float* __restrict__ x, const float* __restrict__ noise,
    const float* __restrict__ Wr, const float* __restrict__ br,
    const float* __restrict__ Wn, const float* __restrict__ bn,
    float* __restrict__ gate, int* __restrict__ slotm)
{
  __shared__ float xs[8][DIN];
  __shared__ float wrs[64][NE];
  __shared__ float wns[64][NE];
  const int tid = threadIdx.x;
  const int t0 = blockIdx.x * 8;
  for (int i = tid; i < 8 * (DIN / 4); i += 256) {
    int tt = i / (DIN / 4), c = i % (DIN / 4);
    ((float4*)xs[tt])[c] = ((const float4*)(x + (size_t)(t0 + tt) * DIN))[c];
  }
  const int lane = tid & 63;
  const int wv = tid >> 6;
  const int e = lane;
  const int ta = 2 * wv, tb = ta + 1;
  float ar0 = br[e], ar1 = ar0, an0 = bn[e], an1 = an0;
  for (int d0 = 0; d0 < DIN; d0 += 64) {
    __syncthreads();
    for (int i = tid; i < 64 * NE / 4; i += 256) {
      int dd = i >> 4, c4 = (i & 15) * 4;
      *(float4*)&wrs[dd][c4] = *(const float4*)&Wr[(size_t)(d0 + dd) * NE + c4];
      *(float4*)&wns[dd][c4] = *(const float4*)&Wn[(size_t)(d0 + dd) * NE + c4];
    }
    __syncthreads();
    #pragma unroll 8
    for (int dd = 0; dd < 64; dd++) {
      float wr = wrs[dd][e], wn = wns[dd][e];
      float xa = xs[ta][d0 + dd], xb = xs[tb][d0 + dd];
      ar0 = fmaf(xa, wr, ar0); ar1 = fmaf(xb, wr, ar1);
      an0 = fmaf(xa, wn, an0); an1 = fmaf(xb, wn, an1);
    }
  }
  #pragma unroll
  for (int s = 0; s < 2; s++) {
    int t = t0 + ta + s;
    float lr = s ? ar1 : ar0;
    float lnv = s ? an1 : an0;
    float sp = fmaxf(lnv, 0.f) + log1pf(expf(-fabsf(lnv)));   // softplus, overflow-safe
    float v = lr + noise[(size_t)t * NE + e] * sp;
    float cur = v;
    float topv[KTOP]; int topi[KTOP];
    #pragma unroll
    for (int j = 0; j < KTOP; j++) {
      float bv = cur; int bi = e;
      #pragma unroll
      for (int off = 32; off > 0; off >>= 1) {
        float ov = __shfl_xor(bv, off);
        int   oi = __shfl_xor(bi, off);
        if (ov > bv || (ov == bv && oi < bi)) { bv = ov; bi = oi; }
      }
      topv[j] = bv; topi[j] = bi;
      if (e == bi) cur = -INFINITY;
    }
    float mx = topv[0], se = 0.f, pv[KTOP];
    #pragma unroll
    for (int j = 0; j < KTOP; j++) { pv[j] = expf(topv[j] - mx); se += pv[j]; }
    float inv = 1.f / se;
    float g = 0.f; int sl = -1;
    #pragma unroll
    for (int j = 0; j < KTOP; j++) if (topi[j] == e) { g = pv[j] * inv; sl = j; }
    gate[(size_t)t * NE + e] = (sl >= 0) ? g : 0.f;
    slotm[(size_t)t * NE + e] = sl;
  }
}

// ---------------- dispatch: stable per-expert compaction (== stable argsort) -------
__global__ __launch_bounds__(256) void dispatch_kernel(
    const float* __restrict__ gate, const int* __restrict__ slotm,
    int* __restrict__ tok_idx, float* __restrict__ tok_g,
    int* __restrict__ tok_slot, int* __restrict__ counts)
{
  const int e = blockIdx.x;
  const int tid = threadIdx.x;
  __shared__ int wave_off[4];
  int base = 0;
  for (int t0 = 0; t0 < T_TOK; t0 += 256) {
    int t = t0 + tid;
    float g = gate[(size_t)t * NE + e];
    bool p = g > 0.f;
    unsigned long long m = __ballot(p);
    int wv = tid >> 6, lane = tid & 63;
    int pre = __popcll(m & ((1ull << lane) - 1ull));
    if (lane == 0) wave_off[wv] = __popcll(m);
    __syncthreads();
    int off = 0;
    for (int w = 0; w < wv; w++) off += wave_off[w];
    int tot = wave_off[0] + wave_off[1] + wave_off[2] + wave_off[3];
    if (p) {
      int pos = base + off + pre;
      if (pos < CAPC) {
        tok_idx[(size_t)e * CAPC + pos] = t;
        tok_g[(size_t)e * CAPC + pos] = g;
        tok_slot[(size_t)e * CAPC + pos] = slotm[(size_t)t * NE + e];
      }
    }
    base += tot;
    __syncthreads();
  }
  if (tid == 0) counts[e] = min(base, CAPC);
}

// ============== GEMM on retiled bf16 B: 256x128x32, both operands gload_lds ========
// 512 thr / 8 waves; all waves stage A (2 glds16) + B (1 glds16) per K-step from
// DENSE streams; 3 LDS buffers (72 KB -> 2 blocks/CU); depth-2 vmcnt(3) pipeline;
// XCD-grouped block decode. B fragment read: section lg, col rotated by +lg
// (conflict-free: 8 lanes per bank-quad = b128 floor).
template<int KD, int ND, bool AGATHER, int EPI, int NBN, int BPE>
__global__ __launch_bounds__(512, 2) void moe_gemm_t2(
    const unsigned short* __restrict__ Abf, const unsigned short* __restrict__ Bt,
    const float* __restrict__ bias, void* __restrict__ Outp,
    const int* __restrict__ tok_idx, const float* __restrict__ tok_g,
    const int* __restrict__ tok_slot, const int* __restrict__ counts)
{
  constexpr int NK = KD / 32;
  constexpr int NP = ND / 128;
  const int bid = blockIdx.x;
  const int xcd = bid & 7;
  const int qd  = bid >> 3;
  const int e     = (qd / BPE) * 8 + xcd;
  const int inner = qd % BPE;
  const int n0p = inner % NBN;
  const int m0  = (inner / NBN) * 256;
  const int n0  = n0p * 128;
  const int cnt = counts[e];
  if (m0 >= cnt) return;
  const int tid = threadIdx.x;
  const int lane = tid & 63, wave = tid >> 6;

  __shared__ unsigned short AL[3][256][32];   // 48 KB
  __shared__ unsigned short BL[3][4096];      // 24 KB
  __shared__ int   s_tok[EPI == 2 ? 256 : 1];
  __shared__ float s_g[EPI == 2 ? 256 : 1];
  __shared__ int   s_slot[EPI == 2 ? 256 : 1];

  if (EPI == 2 && tid < 256) {
    int gr = m0 + tid;
    if (gr < cnt) {
      s_tok[tid]  = tok_idx[(size_t)e * CAPC + gr];
      s_g[tid]    = tok_g[(size_t)e * CAPC + gr];
      s_slot[tid] = tok_slot[(size_t)e * CAPC + gr];
    }
  }

  // A staging: wave stages rows [32w,32w+32); lane -> row 32w+16j+(lane>>2),
  // slot lane&3 holds global chunk ((lane&3)-((row>>1)&3))&3 (conflict-free reads)
  size_t a_src[2];
  #pragma unroll
  for (int j = 0; j < 2; j++) {
    int r = 32 * wave + 16 * j + (lane >> 2);
    int c = ((lane & 3) - ((r >> 1) & 3)) & 3;
    size_t rowb;
    if (AGATHER) {
      int gr = m0 + r;
      int tk = (gr < cnt) ? tok_idx[(size_t)e * CAPC + gr] : 0;
      rowb = (size_t)tk * KD;
    } else {
      rowb = ((size_t)e * CAPC + m0 + r) * KD;
    }
    a_src[j] = rowb + 8 * c;
  }
  const int a_dst0 = (32 * wave) * 32;
  const int a_dst1 = (32 * wave + 16) * 32;
  // B staging: wave stages 1KB of the contiguous 8KB tile
  const unsigned short* b_src = Bt + ((size_t)(e * NP + n0p) * NK) * 4096 + wave * 512 + lane * 8;
  const int b_dst = wave * 512;

  auto stage = [&](int t, unsigned short* Abuf, unsigned short* Bbuf) {
    glds16(Abuf + a_dst0, Abf + a_src[0] + (size_t)t * 32);
    glds16(Abuf + a_dst1, Abf + a_src[1] + (size_t)t * 32);
    glds16(Bbuf + b_dst, b_src + (size_t)t * 4096);
  };

  const int wm = (wave >> 1) * 64, wn = (wave & 1) * 64;
  const int li = lane & 15, lg = lane >> 4;
  const int kxa = 8 * ((lg + ((li >> 1) & 3)) & 3);
  int jb_[4];
  #pragma unroll
  for (int ni = 0; ni < 4; ni++)
    jb_[ni] = lg * 1024 + (((wn + ni * 16 + li) + lg) & 127) * 8;

  f32x4 acc[4][4];
  #pragma unroll
  for (int i = 0; i < 4; i++)
    #pragma unroll
    for (int j = 0; j < 4; j++) acc[i][j] = (f32x4){0.f, 0.f, 0.f, 0.f};

  auto step = [&](const unsigned short* Abuf, const unsigned short* Bbuf) {
    bf16x8 afr[4], bfr[4];
    #pragma unroll
    for (int mi = 0; mi < 4; mi++)
      afr[mi] = *(const bf16x8*)(Abuf + (wm + 16 * mi + li) * 32 + kxa);
    #pragma unroll
    for (int ni = 0; ni < 4; ni++)
      bfr[ni] = *(const bf16x8*)(Bbuf + jb_[ni]);
    __builtin_amdgcn_s_setprio(1);
    #pragma unroll
    for (int mi = 0; mi < 4; mi++)
      #pragma unroll
      for (int ni = 0; ni < 4; ni++)
        acc[mi][ni] = __builtin_amdgcn_mfma_f32_16x16x32_bf16(afr[mi], bfr[ni], acc[mi][ni], 0, 0, 0);
    __builtin_amdgcn_s_setprio(0);
  };

  unsigned short *A0 = &AL[0][0][0], *A1 = &AL[1][0][0], *A2 = &AL[2][0][0];
  unsigned short *B0 = &BL[0][0], *B1 = &BL[1][0], *B2 = &BL[2][0];

  stage(0, A0, B0);
  stage(1, A1, B1);
  asm volatile("s_waitcnt vmcnt(3)" ::: "memory");   // tile 0 landed
  __builtin_amdgcn_s_barrier();

  for (int kt = 0; kt < NK; kt++) {
    const int tn = (kt + 2 < NK) ? kt + 2 : NK - 1;
    stage(tn, A2, B2);
    step(A0, B0);
    asm volatile("s_waitcnt vmcnt(3)" ::: "memory");  // tile kt+1 landed
    __builtin_amdgcn_s_barrier();
    unsigned short* ta = A0; A0 = A1; A1 = A2; A2 = ta;
    unsigned short* tb = B0; B0 = B1; B1 = B2; B2 = tb;
  }
  asm volatile("s_waitcnt vmcnt(0)" ::: "memory");   // drain before WG exit

  const float* bpb = bias + (size_t)e * ND;
  #pragma unroll
  for (int mi = 0; mi < 4; mi++) {
    #pragma unroll
    for (int ni = 0; ni < 4; ni++) {
      const int ncol = n0 + wn + ni * 16 + li;
      const float bb = bpb[ncol];
      #pragma unroll
      for (int qq = 0; qq < 4; qq++) {
        const int r = wm + mi * 16 + lg * 4 + qq;
        const int gr = m0 + r;
        if (gr < cnt) {
          float v = acc[mi][ni][qq] + bb;
          if (EPI == 0) {
            v = gelu_exact(v);
            ((unsigned short*)Outp)[((size_t)e * CAPC + gr) * ND + ncol] = f2bf(v);
          } else if (EPI == 1) {
            ((unsigned short*)Outp)[((size_t)e * CAPC + gr) * ND + ncol] = f2bf(v);
          } else {
            ((float*)Outp)[((size_t)s_tok[r] * KTOP + s_slot[r]) * OD + ncol] = v * s_g[r];
          }
        }
      }
    }
  }
}

// ============== fallback (r9) kernels — used only if workspace is too small ========
template<int KD, int NDT, bool AGATHER, int EPI, int NBN, int BPE>
__global__ __launch_bounds__(512, 2) void moe_gemm_big(
    const unsigned short* __restrict__ Abf, const float* __restrict__ Bw,
    const float* __restrict__ bias, void* __restrict__ Outp,
    const int* __restrict__ tok_idx, const float* __restrict__ tok_g,
    const int* __restrict__ tok_slot, const int* __restrict__ counts)
{
  constexpr int NK = KD / 32;
  static_assert(NK % 4 == 0 && NK >= 8, "NK must be multiple of 4");
  const int bid = blockIdx.x;
  const int xcd = bid & 7;
  const int q   = bid >> 3;
  const int e     = (q / BPE) * 8 + xcd;
  const int inner = q % BPE;
  const int n0 = (inner % NBN) * 128;
  const int m0 = (inner / NBN) * 256;
  const int cnt = counts[e];
  if (m0 >= cnt) return;
  const int tid = threadIdx.x;
  const int lane = tid & 63, wave = tid >> 6;

  __shared__ unsigned short AL[3][256][32];
  __shared__ unsigned short BL[2][128][40];
  __shared__ int   s_tok[EPI == 2 ? 256 : 1];
  __shared__ float s_g[EPI == 2 ? 256 : 1];
  __shared__ int   s_slot[EPI == 2 ? 256 : 1];

  if (EPI == 2 && tid < 256) {
    int gr = m0 + tid;
    if (gr < cnt) {
      s_tok[tid]  = tok_idx[(size_t)e * CAPC + gr];
      s_g[tid]    = tok_g[(size_t)e * CAPC + gr];
      s_slot[tid] = tok_slot[(size_t)e * CAPC + gr];
    }
  }

  const bool isB = wave < 4;
  const int  w4  = wave & 3;
  const float* bp = Bw + (size_t)e * KD * NDT + (size_t)(8 * w4) * NDT + n0 + 2 * lane;
  float2 breg[4][8];

  size_t a_off[4];
  if (!isB) {
    #pragma unroll
    for (int qq = 0; qq < 4; qq++) {
      int r  = w4 * 64 + qq * 16 + (lane >> 2);
      int cq = ((lane & 3) - (r >> 1)) & 3;
      size_t rowb;
      if (AGATHER) {
        int gr = m0 + r;
        int tk = (gr < cnt) ? tok_idx[(size_t)e * CAPC + gr] : 0;
        rowb = (size_t)tk * KD;
      } else {
        rowb = ((size_t)e * CAPC + m0 + r) * KD;
      }
      a_off[qq] = rowb + 8 * cq;
    }
  }

  auto stageA = [&](int t, unsigned short* Abuf) {
    #pragma unroll
    for (int qq = 0; qq < 4; qq++)
      glds16(Abuf + w4 * 2048 + qq * 512, Abf + a_off[qq] + (size_t)t * 32);
  };
  auto loadB = [&](int t, int p) {
    const float* pb = bp + (size_t)t * 32 * NDT;
    #pragma unroll
    for (int j = 0; j < 8; j++) breg[p][j] = *(const float2*)(pb + (size_t)j * NDT);
  };
  auto writeB = [&](unsigned short* Bbuf, int p) {
    uint4 rx, ry;
    rx.x = cvt2(breg[p][0].x, breg[p][1].x); rx.y = cvt2(breg[p][2].x, breg[p][3].x);
    rx.z = cvt2(breg[p][4].x, breg[p][5].x); rx.w = cvt2(breg[p][6].x, breg[p][7].x);
    ry.x = cvt2(breg[p][0].y, breg[p][1].y); ry.y = cvt2(breg[p][2].y, breg[p][3].y);
    ry.z = cvt2(breg[p][4].y, breg[p][5].y); ry.w = cvt2(breg[p][6].y, breg[p][7].y);
    *(uint4*)(Bbuf + (2 * lane) * 40 + 8 * w4)     = rx;
    *(uint4*)(Bbuf + (2 * lane + 1) * 40 + 8 * w4) = ry;
  };

  const int wm = (wave >> 1) * 64;
  const int wn = (wave & 1) * 64;
  const int li = lane & 15, lg = lane >> 4;
  const int kxa = 8 * ((lg + ((li >> 1) & 3)) & 3);

  f32x4 acc[4][4];
  #pragma unroll
  for (int i = 0; i < 4; i++)
    #pragma unroll
    for (int j = 0; j < 4; j++) acc[i][j] = (f32x4){0.f, 0.f, 0.f, 0.f};

  auto step = [&](const unsigned short* Abuf, const unsigned short* Bbuf) {
    bf16x8 afr[4], bfr[4];
    #pragma unroll
    for (int mi = 0; mi < 4; mi++)
      afr[mi] = *(const bf16x8*)(Abuf + (wm + mi * 16 + li) * 32 + kxa);
    #pragma unroll
    for (int ni = 0; ni < 4; ni++)
      bfr[ni] = *(const bf16x8*)(Bbuf + (wn + ni * 16 + li) * 40 + lg * 8);
    __builtin_amdgcn_s_setprio(1);
    #pragma unroll
    for (int mi = 0; mi < 4; mi++)
      #pragma unroll
      for (int ni = 0; ni < 4; ni++)
        acc[mi][ni] = __builtin_amdgcn_mfma_f32_16x16x32_bf16(afr[mi], bfr[ni], acc[mi][ni], 0, 0, 0);
    __builtin_amdgcn_s_setprio(0);
  };

  unsigned short *A0 = &AL[0][0][0], *A1 = &AL[1][0][0], *A2 = &AL[2][0][0];
  unsigned short *B0 = &BL[0][0][0], *B1 = &BL[1][0][0];

  if (isB) {
    loadB(0, 0); loadB(1, 1); loadB(2, 2);
    asm volatile("s_waitcnt vmcnt(16)" ::: "memory");
    writeB(B0, 0);
    asm volatile("s_waitcnt lgkmcnt(0)" ::: "memory");
  } else {
    stageA(0, A0); stageA(1, A1);
    asm volatile("s_waitcnt vmcnt(4)" ::: "memory");
  }
  __builtin_amdgcn_s_barrier();

  #define SUBITER(p)                                                        \
    do {                                                                    \
      const int jj = jb + (p);                                              \
      if (isB) loadB(min(jj + 3, NK - 1), ((p) + 3) & 3);                   \
      else     stageA(min(jj + 2, NK - 1), A2);                             \
      step(A0, B0);                                                         \
      if (isB) {                                                            \
        asm volatile("s_waitcnt vmcnt(16)" ::: "memory");                   \
        writeB(B1, ((p) + 1) & 3);                                          \
        asm volatile("s_waitcnt lgkmcnt(0)" ::: "memory");                  \
      } else {                                                              \
        asm volatile("s_waitcnt vmcnt(4)" ::: "memory");                    \
      }                                                                     \
      __builtin_amdgcn_s_barrier();                                         \
      unsigned short* ta = A0; A0 = A1; A1 = A2; A2 = ta;                   \
      unsigned short* tb = B0; B0 = B1; B1 = tb;                            \
    } while (0)

  for (int jb = 0; jb < NK; jb += 4) {
    SUBITER(0); SUBITER(1); SUBITER(2); SUBITER(3);
  }
  #undef SUBITER
  asm volatile("s_waitcnt vmcnt(0)" ::: "memory");

  const float* bpb = bias + (size_t)e * NDT;
  #pragma unroll
  for (int mi = 0; mi < 4; mi++) {
    #pragma unroll
    for (int ni = 0; ni < 4; ni++) {
      const int ncol = n0 + wn + ni * 16 + li;
      const float bb = bpb[ncol];
      #pragma unroll
      for (int qq = 0; qq < 4; qq++) {
        const int r = wm + mi * 16 + lg * 4 + qq;
        const int gr = m0 + r;
        if (gr < cnt) {
          float v = acc[mi][ni][qq] + bb;
          if (EPI == 0) {
            v = gelu_exact(v);
            ((unsigned short*)Outp)[((size_t)e * CAPC + gr) * NDT + ncol] = f2bf(v);
          } else if (EPI == 1) {
            ((unsigned short*)Outp)[((size_t)e * CAPC + gr) * NDT + ncol] = f2bf(v);
          } else {
            ((float*)Outp)[((size_t)s_tok[r] * KTOP + s_slot[r]) * OD + ncol] = v * s_g[r];
          }
        }
      }
    }
  }
}

// ---------------- combine 8 slots + LayerNorm -------------------------------------
__global__ __launch_bounds__(256) void combine_ln(
    const float* __restrict__ yd, const float* __restrict__ lw,
    const float* __restrict__ lb, float* __restrict__ out)
{
  const int t = blockIdx.x, tid = threadIdx.x;
  float v[3];
  #pragma unroll
  for (int i = 0; i < 3; i++) {
    const int c = tid + 256 * i;
    float s = 0.f;
    #pragma unroll
    for (int j = 0; j < KTOP; j++) s += yd[((size_t)t * KTOP + j) * OD + c];
    v[i] = s;
  }
  float s1 = v[0] + v[1] + v[2];
  float s2 = v[0] * v[0] + v[1] * v[1] + v[2] * v[2];
  #pragma unroll
  for (int off = 32; off > 0; off >>= 1) {
    s1 += __shfl_xor(s1, off);
    s2 += __shfl_xor(s2, off);
  }
  __shared__ float as1[4], as2[4];
  const int lane = tid & 63, wv = tid >> 6;
  if (lane == 0) { as1[wv] = s1; as2[wv] = s2; }
  __syncthreads();
  s1 = as1[0] + as1[1] + as1[2] + as1[3];
  s2 = as2[0] + as2[1] + as2[2] + as2[3];
  const float mu = s1 * (1.f / OD);
  const float var = s2 * (1.f / OD) - mu * mu;
  const float rstd = rsqrtf(var + 1e-5f);
  #pragma unroll
  for (int i = 0; i < 3; i++) {
    const int c = tid + 256 * i;
    out[(size_t)t * OD + c] = (v[i] - mu) * rstd * lw[c] + lb[c];
  }
}

extern "C" void kernel_launch(void* const* d_in, const int* in_sizes, int n_in,
                              void* d_out, int out_size, void* d_ws, size_t ws_size,
                              hipStream_t stream) {
  const float* x     = (const float*)d_in[0];
  const float* noise = (const float*)d_in[1];
  const float* Wr    = (const float*)d_in[2];
  const float* br    = (const float*)d_in[3];
  const float* Wn    = (const float*)d_in[4];
  const float* bn    = (const float*)d_in[5];
  const float* W1    = (const float*)d_in[6];
  const float* b1    = (const float*)d_in[7];
  const float* W2    = (const float*)d_in[8];
  const float* b2    = (const float*)d_in[9];
  const float* W3    = (const float*)d_in[10];
  const float* b3    = (const float*)d_in[11];
  const float* Wo    = (const float*)d_in[12];
  const float* bo    = (const float*)d_in[13];
  const float* lw    = (const float*)d_in[14];
  const float* lb    = (const float*)d_in[15];
  float* out = (float*)d_out;

  char* ws = (char*)d_ws;
  constexpr size_t OFF_GATE = 0;
  constexpr size_t OFF_SLOT = OFF_GATE + (size_t)T_TOK * NE * 4;
  constexpr size_t OFF_TIDX = OFF_SLOT + (size_t)T_TOK * NE * 4;
  constexpr size_t OFF_TG   = OFF_TIDX + (size_t)NE * CAPC * 4;
  constexpr size_t OFF_TSL  = OFF_TG + (size_t)NE * CAPC * 4;
  constexpr size_t OFF_CNT  = OFF_TSL + (size_t)NE * CAPC * 4;
  constexpr size_t OFF_YD   = ((OFF_CNT + NE * 4) + 255) & ~(size_t)255;
  constexpr size_t SZ_YD    = (size_t)T_TOK * KTOP * OD * 4;
  constexpr size_t OFF_H1   = OFF_YD + SZ_YD;
  constexpr size_t OFF_H2   = OFF_H1 + (size_t)NE * CAPC * HD * 2;
  constexpr size_t OFF_H3   = OFF_H2 + (size_t)NE * CAPC * HD * 2;
  constexpr size_t OFF_XBF  = OFF_H3 + (size_t)NE * CAPC * BTD * 2;
  constexpr size_t OFF_W1T  = ((OFF_XBF + (size_t)T_TOK * DIN * 2) + 255) & ~(size_t)255;
  constexpr size_t SZ_W1T   = (size_t)NE * (HD / 128) * (DIN / 32) * 4096 * 2;  // 201 MB
  constexpr size_t OFF_W2T  = OFF_W1T + SZ_W1T;
  constexpr size_t SZ_W2T   = (size_t)NE * (HD / 128) * (HD / 32) * 4096 * 2;   // 537 MB
  constexpr size_t OFF_W3T  = OFF_W2T + SZ_W2T;
  constexpr size_t SZ_W3T   = (size_t)NE * (BTD / 128) * (HD / 32) * 4096 * 2;  // 67 MB
  constexpr size_t OFF_WOT  = OFF_W3T + SZ_W3T;
  constexpr size_t SZ_WOT   = (size_t)NE * (OD / 128) * (BTD / 32) * 4096 * 2;  // 25 MB
  constexpr size_t NEED     = OFF_WOT + SZ_WOT;

  float* gate = (float*)(ws + OFF_GATE);
  int*   slot = (int*)(ws + OFF_SLOT);
  int*   tidx = (int*)(ws + OFF_TIDX);
  float* tg   = (float*)(ws + OFF_TG);
  int*   tsl  = (int*)(ws + OFF_TSL);
  int*   cnts = (int*)(ws + OFF_CNT);
  float* yd   = (float*)(ws + OFF_YD);
  unsigned short* h1  = (unsigned short*)(ws + OFF_H1);
  unsigned short* h2  = (unsigned short*)(ws + OFF_H2);
  unsigned short* h3  = (unsigned short*)(ws + OFF_H3);
  unsigned short* xbf = (unsigned short*)(ws + OFF_XBF);
  unsigned short* w1t = (unsigned short*)(ws + OFF_W1T);
  unsigned short* w2t = (unsigned short*)(ws + OFF_W2T);
  unsigned short* w3t = (unsigned short*)(ws + OFF_W3T);
  unsigned short* wot = (unsigned short*)(ws + OFF_WOT);

  hipMemsetAsync(yd, 0, SZ_YD, stream);
  cvt_x<<<T_TOK * DIN / 4 / 256, 256, 0, stream>>>(x, xbf);
  router_kernel<<<T_TOK / 8, 256, 0, stream>>>(x, noise, Wr, br, Wn, bn, gate, slot);
  dispatch_kernel<<<NE, 256, 0, stream>>>(gate, slot, tidx, tg, tsl, cnts);

  if (ws_size >= NEED) {
    // dense retile (reads dense full rows, writes contiguous 2KB chunks)
    retile3<DIN, HD><<<dim3(DIN / 8, NE), 256, 0, stream>>>(W1, w1t);
    retile3<HD, HD><<<dim3(HD / 8, NE), 256, 0, stream>>>(W2, w2t);
    retile3<HD, BTD><<<dim3(HD / 8, NE), 256, 0, stream>>>(W3, w3t);
    retile3<BTD, OD><<<dim3(BTD / 8, NE), 256, 0, stream>>>(Wo, wot);
    // all GEMMs on dense bf16 tiles, XCD-grouped, 2 blocks/CU
    moe_gemm_t2<DIN, HD, true, 0, 16, 32><<<2048, 512, 0, stream>>>(
        xbf, w1t, b1, h1, tidx, tg, tsl, cnts);
    moe_gemm_t2<HD, HD, false, 0, 16, 32><<<2048, 512, 0, stream>>>(
        h1, w2t, b2, h2, tidx, tg, tsl, cnts);
    moe_gemm_t2<HD, BTD, false, 1, 2, 4><<<256, 512, 0, stream>>>(
        h2, w3t, b3, h3, tidx, tg, tsl, cnts);
    moe_gemm_t2<BTD, OD, false, 2, 6, 12><<<768, 512, 0, stream>>>(
        h3, wot, bo, yd, tidx, tg, tsl, cnts);
  } else {
    // fallback: r9 path
    moe_gemm_big<DIN, HD, true, 0, 16, 32><<<2048, 512, 0, stream>>>(
        xbf, W1, b1, h1, tidx, tg, tsl, cnts);
    moe_gemm_big<HD, HD, false, 0, 16, 32><<<2048, 512, 0, stream>>>(
        h1, W2, b2, h2, tidx, tg, tsl, cnts);
    moe_gemm_big<HD, BTD, false, 1, 2, 8><<<1024, 512, 0, stream>>>(
        h2, W3, b3, h3, tidx, tg, tsl, cnts);
    moe_gemm_big<BTD, OD, false, 2, 6, 24><<<3072, 512, 0, stream>>>(
        h3, Wo, bo, yd, tidx, tg, tsl, cnts);
  }
  combine_ln<<<T_TOK, 256, 0, stream>>>(yd, lw, lb, out);
}

// Round 11
// 1118.996 us; speedup vs baseline: 1.0343x; 1.0343x over previous
//
#include <hip/hip_runtime.h>
#include <math.h>

#define T_TOK 2048
#define NE 64
#define KTOP 8
#define CAPC 512
#define DIN 768
#define HD 2048
#define BTD 256
#define OD 768

typedef short bf16x8 __attribute__((ext_vector_type(8)));
typedef float f32x4 __attribute__((ext_vector_type(4)));

__device__ __forceinline__ unsigned short f2bf(float f) {
  unsigned u = __float_as_uint(f);
  u += 0x7FFF + ((u >> 16) & 1);   // round-to-nearest-even
  return (unsigned short)(u >> 16);
}
__device__ __forceinline__ unsigned cvt2(float a, float b) {
  unsigned r;
  asm("v_cvt_pk_bf16_f32 %0, %1, %2" : "=v"(r) : "v"(a), "v"(b));
  return r;   // lo = bf16(a), hi = bf16(b)
}
__device__ __forceinline__ float gelu_exact(float v) {
  return 0.5f * v * (1.0f + erff(v * 0.7071067811865476f));
}
__device__ __forceinline__ void glds16(unsigned short* lds, const unsigned short* g) {
  __builtin_amdgcn_global_load_lds(
      (const __attribute__((address_space(1))) void*)g,
      (__attribute__((address_space(3))) void*)lds, 16, 0, 0);
}

// ---------------- x fp32 -> bf16 ---------------------------------------------------
__global__ __launch_bounds__(256) void cvt_x(const float* __restrict__ x,
                                             unsigned short* __restrict__ xb) {
  int i = blockIdx.x * 256 + threadIdx.x;
  float4 v = ((const float4*)x)[i];
  ushort4 o;
  o.x = f2bf(v.x); o.y = f2bf(v.y); o.z = f2bf(v.z); o.w = f2bf(v.w);
  ((ushort4*)xb)[i] = o;
}

// ---------------- retile body (r10-verified format, ROWS-generalized) ---------------
// Tile (e,p,t) = 4096 shorts, q-major; section q holds k-rows 32t+8q..+7;
// pos q*1024 + j*8 + h = bf16 W[32t+8q+h][128p + ((j-q)&127)].
// Block covers ROWS k-rows x full ND: dense reads, contiguous 2KB writes.
template<int KD, int ND, int ROWS>
__device__ __forceinline__ void retile_body(int e, int rg, const float* __restrict__ W,
                                            unsigned short* __restrict__ Bt,
                                            unsigned char* smem)
{
  constexpr int KT = KD / 32;
  constexpr int NP = ND / 128;
  float* L = (float*)smem;                 // ROWS*ND*4 bytes (<= 65536)
  const int tid = threadIdx.x;
  const int r0 = rg * ROWS;
  const float4* src = (const float4*)(W + ((size_t)e * KD + r0) * ND);
  for (int i = tid; i < ROWS * ND / 4; i += 512) ((float4*)L)[i] = src[i];
  __syncthreads();
  unsigned short* oute = Bt + (size_t)e * NP * KT * 4096;
  #pragma unroll
  for (int g = 0; g < ROWS / 8; g++) {
    const int rr = r0 + 8 * g;
    const int t = rr >> 5, q = (rr >> 3) & 3;
    unsigned short* outt = oute + (size_t)t * 4096 + q * 1024;
    for (int ix = tid; ix < ND; ix += 512) {
      int p = ix >> 7, j = ix & 127;
      int col = 128 * p + ((j - q) & 127);
      union { bf16x8 v; unsigned u[4]; } pk;
      #pragma unroll
      for (int h = 0; h < 4; h++)
        pk.u[h] = cvt2(L[(8 * g + 2 * h) * ND + col], L[(8 * g + 2 * h + 1) * ND + col]);
      *(bf16x8*)&outt[(size_t)p * KT * 4096 + j * 8] = pk.v;
    }
  }
}

// ---------------- router: fp32 logits, noisy top-8, softmax, gate/slot matrices ----
__global__ __launch_bounds__(256) void router_kernel(
    const float* __restrict__ x, const float* __restrict__ noise,
    const float* __restrict__ Wr, const float* __restrict__ br,
    const float* __restrict__ Wn, const float* __restrict__ bn,
    float* __restrict__ gate, int* __restrict__ slotm)
{
  __shared__ float xs[8][DIN];
  __shared__ float wrs[64][NE];
  __shared__ float wns[64][NE];
  const int tid = threadIdx.x;
  const int t0 = blockIdx.x * 8;
  for (int i = tid; i < 8 * (DIN / 4); i += 256) {
    int tt = i / (DIN / 4), c = i % (DIN / 4);
    ((float4*)xs[tt])[c] = ((const float4*)(x + (size_t)(t0 + tt) * DIN))[c];
  }
  const int lane = tid & 63;
  const int wv = tid >> 6;
  const int e = lane;
  const int ta = 2 * wv, tb = ta + 1;
  float ar0 = br[e], ar1 = ar0, an0 = bn[e], an1 = an0;
  for (int d0 = 0; d0 < DIN; d0 += 64) {
    __syncthreads();
    for (int i = tid; i < 64 * NE / 4; i += 256) {
      int dd = i >> 4, c4 = (i & 15) * 4;
      *(float4*)&wrs[dd][c4] = *(const float4*)&Wr[(size_t)(d0 + dd) * NE + c4];
      *(float4*)&wns[dd][c4] = *(const float4*)&Wn[(size_t)(d0 + dd) * NE + c4];
    }
    __syncthreads();
    #pragma unroll 8
    for (int dd = 0; dd < 64; dd++) {
      float wr = wrs[dd][e], wn = wns[dd][e];
      float xa = xs[ta][d0 + dd], xb = xs[tb][d0 + dd];
      ar0 = fmaf(xa, wr, ar0); ar1 = fmaf(xb, wr, ar1);
      an0 = fmaf(xa, wn, an0); an1 = fmaf(xb, wn, an1);
    }
  }
  #pragma unroll
  for (int s = 0; s < 2; s++) {
    int t = t0 + ta + s;
    float lr = s ? ar1 : ar0;
    float lnv = s ? an1 : an0;
    float sp = fmaxf(lnv, 0.f) + log1pf(expf(-fabsf(lnv)));   // softplus, overflow-safe
    float v = lr + noise[(size_t)t * NE + e] * sp;
    float cur = v;
    float topv[KTOP]; int topi[KTOP];
    #pragma unroll
    for (int j = 0; j < KTOP; j++) {
      float bv = cur; int bi = e;
      #pragma unroll
      for (int off = 32; off > 0; off >>= 1) {
        float ov = __shfl_xor(bv, off);
        int   oi = __shfl_xor(bi, off);
        if (ov > bv || (ov == bv && oi < bi)) { bv = ov; bi = oi; }
      }
      topv[j] = bv; topi[j] = bi;
      if (e == bi) cur = -INFINITY;
    }
    float mx = topv[0], se = 0.f, pv[KTOP];
    #pragma unroll
    for (int j = 0; j < KTOP; j++) { pv[j] = expf(topv[j] - mx); se += pv[j]; }
    float inv = 1.f / se;
    float g = 0.f; int sl = -1;
    #pragma unroll
    for (int j = 0; j < KTOP; j++) if (topi[j] == e) { g = pv[j] * inv; sl = j; }
    gate[(size_t)t * NE + e] = (sl >= 0) ? g : 0.f;
    slotm[(size_t)t * NE + e] = sl;
  }
}

// ---------------- dispatch: stable per-expert compaction (== stable argsort) -------
__global__ __launch_bounds__(256) void dispatch_kernel(
    const float* __restrict__ gate, const int* __restrict__ slotm,
    int* __restrict__ tok_idx, float* __restrict__ tok_g,
    int* __restrict__ tok_slot, int* __restrict__ counts)
{
  const int e = blockIdx.x;
  const int tid = threadIdx.x;
  __shared__ int wave_off[4];
  int base = 0;
  for (int t0 = 0; t0 < T_TOK; t0 += 256) {
    int t = t0 + tid;
    float g = gate[(size_t)t * NE + e];
    bool p = g > 0.f;
    unsigned long long m = __ballot(p);
    int wv = tid >> 6, lane = tid & 63;
    int pre = __popcll(m & ((1ull << lane) - 1ull));
    if (lane == 0) wave_off[wv] = __popcll(m);
    __syncthreads();
    int off = 0;
    for (int w = 0; w < wv; w++) off += wave_off[w];
    int tot = wave_off[0] + wave_off[1] + wave_off[2] + wave_off[3];
    if (p) {
      int pos = base + off + pre;
      if (pos < CAPC) {
        tok_idx[(size_t)e * CAPC + pos] = t;
        tok_g[(size_t)e * CAPC + pos] = g;
        tok_slot[(size_t)e * CAPC + pos] = slotm[(size_t)t * NE + e];
      }
    }
    base += tot;
    __syncthreads();
  }
  if (tid == 0) counts[e] = min(base, CAPC);
}

// ============== r9-verified big-GEMM body (256x128x32, role-split fp32 B) ==========
// smem layout: ALb = smem[0..49152) (3 x 8192 ushort), BLb = smem[49152..69632)
// (2 x 5120 ushort); s_tok/s_g/s_slot at 69632.. (only touched when EPI==2).
template<int KD, int NDT, bool AGATHER, int EPI, int NBN>
__device__ __forceinline__ void gemm_big_body(
    const int e, const int inner, const int cnt, unsigned char* smem,
    const unsigned short* __restrict__ Abf, const float* __restrict__ Bw,
    const float* __restrict__ bias, void* __restrict__ Outp,
    const int* __restrict__ tok_idx, const float* __restrict__ tok_g,
    const int* __restrict__ tok_slot)
{
  constexpr int NK = KD / 32;
  static_assert(NK % 4 == 0 && NK >= 8, "NK must be multiple of 4");
  const int n0 = (inner % NBN) * 128;
  const int m0 = (inner / NBN) * 256;
  if (m0 >= cnt) return;
  const int tid = threadIdx.x;
  const int lane = tid & 63, wave = tid >> 6;

  unsigned short* ALb = (unsigned short*)smem;
  unsigned short* BLb = (unsigned short*)(smem + 49152);
  int*   s_tok  = (int*)(smem + 69632);
  float* s_g    = (float*)(smem + 70656);
  int*   s_slot = (int*)(smem + 71680);

  if (EPI == 2 && tid < 256) {
    int gr = m0 + tid;
    if (gr < cnt) {
      s_tok[tid]  = tok_idx[(size_t)e * CAPC + gr];
      s_g[tid]    = tok_g[(size_t)e * CAPC + gr];
      s_slot[tid] = tok_slot[(size_t)e * CAPC + gr];
    }
  }

  const bool isB = wave < 4;
  const int  w4  = wave & 3;

  const float* bp = Bw + (size_t)e * KD * NDT + (size_t)(8 * w4) * NDT + n0 + 2 * lane;
  float2 breg[4][8];

  size_t a_off[4];
  if (!isB) {
    #pragma unroll
    for (int qq = 0; qq < 4; qq++) {
      int r  = w4 * 64 + qq * 16 + (lane >> 2);
      int cq = ((lane & 3) - (r >> 1)) & 3;
      size_t rowb;
      if (AGATHER) {
        int gr = m0 + r;
        int tk = (gr < cnt) ? tok_idx[(size_t)e * CAPC + gr] : 0;
        rowb = (size_t)tk * KD;
      } else {
        rowb = ((size_t)e * CAPC + m0 + r) * KD;
      }
      a_off[qq] = rowb + 8 * cq;
    }
  }

  auto stageA = [&](int t, unsigned short* Abuf) {
    #pragma unroll
    for (int qq = 0; qq < 4; qq++)
      glds16(Abuf + w4 * 2048 + qq * 512, Abf + a_off[qq] + (size_t)t * 32);
  };
  auto loadB = [&](int t, int p) {
    const float* pb = bp + (size_t)t * 32 * NDT;
    #pragma unroll
    for (int j = 0; j < 8; j++) breg[p][j] = *(const float2*)(pb + (size_t)j * NDT);
  };
  auto writeB = [&](unsigned short* Bbuf, int p) {
    uint4 rx, ry;
    rx.x = cvt2(breg[p][0].x, breg[p][1].x); rx.y = cvt2(breg[p][2].x, breg[p][3].x);
    rx.z = cvt2(breg[p][4].x, breg[p][5].x); rx.w = cvt2(breg[p][6].x, breg[p][7].x);
    ry.x = cvt2(breg[p][0].y, breg[p][1].y); ry.y = cvt2(breg[p][2].y, breg[p][3].y);
    ry.z = cvt2(breg[p][4].y, breg[p][5].y); ry.w = cvt2(breg[p][6].y, breg[p][7].y);
    *(uint4*)(Bbuf + (2 * lane) * 40 + 8 * w4)     = rx;
    *(uint4*)(Bbuf + (2 * lane + 1) * 40 + 8 * w4) = ry;
  };

  const int wm = (wave >> 1) * 64;
  const int wn = (wave & 1) * 64;
  const int li = lane & 15, lg = lane >> 4;
  const int kxa = 8 * ((lg + ((li >> 1) & 3)) & 3);

  f32x4 acc[4][4];
  #pragma unroll
  for (int i = 0; i < 4; i++)
    #pragma unroll
    for (int j = 0; j < 4; j++) acc[i][j] = (f32x4){0.f, 0.f, 0.f, 0.f};

  auto step = [&](const unsigned short* Abuf, const unsigned short* Bbuf) {
    bf16x8 afr[4], bfr[4];
    #pragma unroll
    for (int mi = 0; mi < 4; mi++)
      afr[mi] = *(const bf16x8*)(Abuf + (wm + mi * 16 + li) * 32 + kxa);
    #pragma unroll
    for (int ni = 0; ni < 4; ni++)
      bfr[ni] = *(const bf16x8*)(Bbuf + (wn + ni * 16 + li) * 40 + lg * 8);
    __builtin_amdgcn_s_setprio(1);
    #pragma unroll
    for (int mi = 0; mi < 4; mi++)
      #pragma unroll
      for (int ni = 0; ni < 4; ni++)
        acc[mi][ni] = __builtin_amdgcn_mfma_f32_16x16x32_bf16(afr[mi], bfr[ni], acc[mi][ni], 0, 0, 0);
    __builtin_amdgcn_s_setprio(0);
  };

  unsigned short *A0 = ALb, *A1 = ALb + 8192, *A2 = ALb + 16384;
  unsigned short *B0 = BLb, *B1 = BLb + 5120;

  if (isB) {
    loadB(0, 0); loadB(1, 1); loadB(2, 2);
    asm volatile("s_waitcnt vmcnt(16)" ::: "memory");
    writeB(B0, 0);
    asm volatile("s_waitcnt lgkmcnt(0)" ::: "memory");
  } else {
    stageA(0, A0); stageA(1, A1);
    asm volatile("s_waitcnt vmcnt(4)" ::: "memory");
  }
  __builtin_amdgcn_s_barrier();

  #define SUBITER(p)                                                        \
    do {                                                                    \
      const int jj = jb + (p);                                              \
      if (isB) loadB(min(jj + 3, NK - 1), ((p) + 3) & 3);                   \
      else     stageA(min(jj + 2, NK - 1), A2);                             \
      step(A0, B0);                                                         \
      if (isB) {                                                            \
        asm volatile("s_waitcnt vmcnt(16)" ::: "memory");                   \
        writeB(B1, ((p) + 1) & 3);                                          \
        asm volatile("s_waitcnt lgkmcnt(0)" ::: "memory");                  \
      } else {                                                              \
        asm volatile("s_waitcnt vmcnt(4)" ::: "memory");                    \
      }                                                                     \
      __builtin_amdgcn_s_barrier();                                         \
      unsigned short* ta = A0; A0 = A1; A1 = A2; A2 = ta;                   \
      unsigned short* tb = B0; B0 = B1; B1 = tb;                            \
    } while (0)

  for (int jb = 0; jb < NK; jb += 4) {
    SUBITER(0); SUBITER(1); SUBITER(2); SUBITER(3);
  }
  #undef SUBITER
  asm volatile("s_waitcnt vmcnt(0)" ::: "memory");

  const float* bpb = bias + (size_t)e * NDT;
  #pragma unroll
  for (int mi = 0; mi < 4; mi++) {
    #pragma unroll
    for (int ni = 0; ni < 4; ni++) {
      const int ncol = n0 + wn + ni * 16 + li;
      const float bb = bpb[ncol];
      #pragma unroll
      for (int qq = 0; qq < 4; qq++) {
        const int r = wm + mi * 16 + lg * 4 + qq;
        const int gr = m0 + r;
        if (gr < cnt) {
          float v = acc[mi][ni][qq] + bb;
          if (EPI == 0) {
            v = gelu_exact(v);
            ((unsigned short*)Outp)[((size_t)e * CAPC + gr) * NDT + ncol] = f2bf(v);
          } else if (EPI == 1) {
            ((unsigned short*)Outp)[((size_t)e * CAPC + gr) * NDT + ncol] = f2bf(v);
          } else {
            ((float*)Outp)[((size_t)s_tok[r] * KTOP + s_slot[r]) * OD + ncol] = v * s_g[r];
          }
        }
      }
    }
  }
}

// ---------------- fallback wrapper (strided fp32, r9 path) -------------------------
template<int KD, int NDT, bool AGATHER, int EPI, int NBN, int BPE>
__global__ __launch_bounds__(512, 2) void moe_gemm_big(
    const unsigned short* __restrict__ Abf, const float* __restrict__ Bw,
    const float* __restrict__ bias, void* __restrict__ Outp,
    const int* __restrict__ tok_idx, const float* __restrict__ tok_g,
    const int* __restrict__ tok_slot, const int* __restrict__ counts)
{
  __shared__ __align__(16) unsigned char smem[72704];
  const int bid = blockIdx.x;
  const int xcd = bid & 7, q = bid >> 3;
  const int e = (q / BPE) * 8 + xcd;
  gemm_big_body<KD, NDT, AGATHER, EPI, NBN>(e, q % BPE, counts[e], smem,
      Abf, Bw, bias, Outp, tok_idx, tok_g, tok_slot);
}

// ============== fused kernel A: GEMM1 (fp32 W1) || retile W2/W3/Wo =================
// Per-XCD decode: idx<256 -> GEMM1 block (8 experts/xcd x 32 tiles, r9 geometry,
// dispatched first); idx>=256 -> retile block. No data dependency between roles.
__global__ __launch_bounds__(512, 2) void fusedA(
    const unsigned short* __restrict__ xbf, const float* __restrict__ W1,
    const float* __restrict__ b1, unsigned short* __restrict__ h1,
    const float* __restrict__ W2, unsigned short* __restrict__ w2t,
    const float* __restrict__ W3, unsigned short* __restrict__ w3t,
    const float* __restrict__ Wo, unsigned short* __restrict__ wot,
    const int* __restrict__ tidx, const float* __restrict__ tg,
    const int* __restrict__ tsl, const int* __restrict__ cnts)
{
  __shared__ __align__(16) unsigned char smem[69632];
  const int bid = blockIdx.x;
  const int xcd = bid & 7, idx = bid >> 3;
  if (idx < 256) {
    const int e = (idx >> 5) * 8 + xcd;
    gemm_big_body<DIN, HD, true, 0, 16>(e, idx & 31, cnts[e], smem,
        xbf, W1, b1, h1, tidx, tg, tsl);
  } else {
    const int rid = xcd * 2816 + (idx - 256);
    if (rid < 16384) {
      retile_body<HD, HD, 8>(rid >> 8, rid & 255, W2, w2t, smem);       // 16384 blocks
    } else if (rid < 20480) {
      const int r = rid - 16384;
      retile_body<HD, BTD, 32>(r >> 6, r & 63, W3, w3t, smem);          // 4096 blocks
    } else {
      const int r = rid - 20480;
      retile_body<BTD, OD, 8>(r >> 5, r & 31, Wo, wot, smem);           // 2048 blocks
    }
  }
}

// ============== GEMM on retiled bf16 B (r10-verified): 256x128x32 ==================
template<int KD, int ND, bool AGATHER, int EPI, int NBN, int BPE>
__global__ __launch_bounds__(512, 2) void moe_gemm_t2(
    const unsigned short* __restrict__ Abf, const unsigned short* __restrict__ Bt,
    const float* __restrict__ bias, void* __restrict__ Outp,
    const int* __restrict__ tok_idx, const float* __restrict__ tok_g,
    const int* __restrict__ tok_slot, const int* __restrict__ counts)
{
  constexpr int NK = KD / 32;
  constexpr int NP = ND / 128;
  const int bid = blockIdx.x;
  const int xcd = bid & 7;
  const int qd  = bid >> 3;
  const int e     = (qd / BPE) * 8 + xcd;
  const int inner = qd % BPE;
  const int n0p = inner % NBN;
  const int m0  = (inner / NBN) * 256;
  const int n0  = n0p * 128;
  const int cnt = counts[e];
  if (m0 >= cnt) return;
  const int tid = threadIdx.x;
  const int lane = tid & 63, wave = tid >> 6;

  __shared__ unsigned short AL[3][256][32];   // 48 KB
  __shared__ unsigned short BL[3][4096];      // 24 KB
  __shared__ int   s_tok[EPI == 2 ? 256 : 1];
  __shared__ float s_g[EPI == 2 ? 256 : 1];
  __shared__ int   s_slot[EPI == 2 ? 256 : 1];

  if (EPI == 2 && tid < 256) {
    int gr = m0 + tid;
    if (gr < cnt) {
      s_tok[tid]  = tok_idx[(size_t)e * CAPC + gr];
      s_g[tid]    = tok_g[(size_t)e * CAPC + gr];
      s_slot[tid] = tok_slot[(size_t)e * CAPC + gr];
    }
  }

  size_t a_src[2];
  #pragma unroll
  for (int j = 0; j < 2; j++) {
    int r = 32 * wave + 16 * j + (lane >> 2);
    int c = ((lane & 3) - ((r >> 1) & 3)) & 3;
    size_t rowb;
    if (AGATHER) {
      int gr = m0 + r;
      int tk = (gr < cnt) ? tok_idx[(size_t)e * CAPC + gr] : 0;
      rowb = (size_t)tk * KD;
    } else {
      rowb = ((size_t)e * CAPC + m0 + r) * KD;
    }
    a_src[j] = rowb + 8 * c;
  }
  const int a_dst0 = (32 * wave) * 32;
  const int a_dst1 = (32 * wave + 16) * 32;
  const unsigned short* b_src = Bt + ((size_t)(e * NP + n0p) * NK) * 4096 + wave * 512 + lane * 8;
  const int b_dst = wave * 512;

  auto stage = [&](int t, unsigned short* Abuf, unsigned short* Bbuf) {
    glds16(Abuf + a_dst0, Abf + a_src[0] + (size_t)t * 32);
    glds16(Abuf + a_dst1, Abf + a_src[1] + (size_t)t * 32);
    glds16(Bbuf + b_dst, b_src + (size_t)t * 4096);
  };

  const int wm = (wave >> 1) * 64, wn = (wave & 1) * 64;
  const int li = lane & 15, lg = lane >> 4;
  const int kxa = 8 * ((lg + ((li >> 1) & 3)) & 3);
  int jb_[4];
  #pragma unroll
  for (int ni = 0; ni < 4; ni++)
    jb_[ni] = lg * 1024 + (((wn + ni * 16 + li) + lg) & 127) * 8;

  f32x4 acc[4][4];
  #pragma unroll
  for (int i = 0; i < 4; i++)
    #pragma unroll
    for (int j = 0; j < 4; j++) acc[i][j] = (f32x4){0.f, 0.f, 0.f, 0.f};

  auto step = [&](const unsigned short* Abuf, const unsigned short* Bbuf) {
    bf16x8 afr[4], bfr[4];
    #pragma unroll
    for (int mi = 0; mi < 4; mi++)
      afr[mi] = *(const bf16x8*)(Abuf + (wm + 16 * mi + li) * 32 + kxa);
    #pragma unroll
    for (int ni = 0; ni < 4; ni++)
      bfr[ni] = *(const bf16x8*)(Bbuf + jb_[ni]);
    __builtin_amdgcn_s_setprio(1);
    #pragma unroll
    for (int mi = 0; mi < 4; mi++)
      #pragma unroll
      for (int ni = 0; ni < 4; ni++)
        acc[mi][ni] = __builtin_amdgcn_mfma_f32_16x16x32_bf16(afr[mi], bfr[ni], acc[mi][ni], 0, 0, 0);
    __builtin_amdgcn_s_setprio(0);
  };

  unsigned short *A0 = &AL[0][0][0], *A1 = &AL[1][0][0], *A2 = &AL[2][0][0];
  unsigned short *B0 = &BL[0][0], *B1 = &BL[1][0], *B2 = &BL[2][0];

  stage(0, A0, B0);
  stage(1, A1, B1);
  asm volatile("s_waitcnt vmcnt(3)" ::: "memory");
  __builtin_amdgcn_s_barrier();

  for (int kt = 0; kt < NK; kt++) {
    const int tn = (kt + 2 < NK) ? kt + 2 : NK - 1;
    stage(tn, A2, B2);
    step(A0, B0);
    asm volatile("s_waitcnt vmcnt(3)" ::: "memory");
    __builtin_amdgcn_s_barrier();
    unsigned short* ta = A0; A0 = A1; A1 = A2; A2 = ta;
    unsigned short* tb = B0; B0 = B1; B1 = B2; B2 = tb;
  }
  asm volatile("s_waitcnt vmcnt(0)" ::: "memory");

  const float* bpb = bias + (size_t)e * ND;
  #pragma unroll
  for (int mi = 0; mi < 4; mi++) {
    #pragma unroll
    for (int ni = 0; ni < 4; ni++) {
      const int ncol = n0 + wn + ni * 16 + li;
      const float bb = bpb[ncol];
      #pragma unroll
      for (int qq = 0; qq < 4; qq++) {
        const int r = wm + mi * 16 + lg * 4 + qq;
        const int gr = m0 + r;
        if (gr < cnt) {
          float v = acc[mi][ni][qq] + bb;
          if (EPI == 0) {
            v = gelu_exact(v);
            ((unsigned short*)Outp)[((size_t)e * CAPC + gr) * ND + ncol] = f2bf(v);
          } else if (EPI == 1) {
            ((unsigned short*)Outp)[((size_t)e * CAPC + gr) * ND + ncol] = f2bf(v);
          } else {
            ((float*)Outp)[((size_t)s_tok[r] * KTOP + s_slot[r]) * OD + ncol] = v * s_g[r];
          }
        }
      }
    }
  }
}

// ---------------- combine 8 slots + LayerNorm -------------------------------------
__global__ __launch_bounds__(256) void combine_ln(
    const float* __restrict__ yd, const float* __restrict__ lw,
    const float* __restrict__ lb, float* __restrict__ out)
{
  const int t = blockIdx.x, tid = threadIdx.x;
  float v[3];
  #pragma unroll
  for (int i = 0; i < 3; i++) {
    const int c = tid + 256 * i;
    float s = 0.f;
    #pragma unroll
    for (int j = 0; j < KTOP; j++) s += yd[((size_t)t * KTOP + j) * OD + c];
    v[i] = s;
  }
  float s1 = v[0] + v[1] + v[2];
  float s2 = v[0] * v[0] + v[1] * v[1] + v[2] * v[2];
  #pragma unroll
  for (int off = 32; off > 0; off >>= 1) {
    s1 += __shfl_xor(s1, off);
    s2 += __shfl_xor(s2, off);
  }
  __shared__ float as1[4], as2[4];
  const int lane = tid & 63, wv = tid >> 6;
  if (lane == 0) { as1[wv] = s1; as2[wv] = s2; }
  __syncthreads();
  s1 = as1[0] + as1[1] + as1[2] + as1[3];
  s2 = as2[0] + as2[1] + as2[2] + as2[3];
  const float mu = s1 * (1.f / OD);
  const float var = s2 * (1.f / OD) - mu * mu;
  const float rstd = rsqrtf(var + 1e-5f);
  #pragma unroll
  for (int i = 0; i < 3; i++) {
    const int c = tid + 256 * i;
    out[(size_t)t * OD + c] = (v[i] - mu) * rstd * lw[c] + lb[c];
  }
}

extern "C" void kernel_launch(void* const* d_in, const int* in_sizes, int n_in,
                              void* d_out, int out_size, void* d_ws, size_t ws_size,
                              hipStream_t stream) {
  const float* x     = (const float*)d_in[0];
  const float* noise = (const float*)d_in[1];
  const float* Wr    = (const float*)d_in[2];
  const float* br    = (const float*)d_in[3];
  const float* Wn    = (const float*)d_in[4];
  const float* bn    = (const float*)d_in[5];
  const float* W1    = (const float*)d_in[6];
  const float* b1    = (const float*)d_in[7];
  const float* W2    = (const float*)d_in[8];
  const float* b2    = (const float*)d_in[9];
  const float* W3    = (const float*)d_in[10];
  const float* b3    = (const float*)d_in[11];
  const float* Wo    = (const float*)d_in[12];
  const float* bo    = (const float*)d_in[13];
  const float* lw    = (const float*)d_in[14];
  const float* lb    = (const float*)d_in[15];
  float* out = (float*)d_out;

  char* ws = (char*)d_ws;
  constexpr size_t OFF_GATE = 0;
  constexpr size_t OFF_SLOT = OFF_GATE + (size_t)T_TOK * NE * 4;
  constexpr size_t OFF_TIDX = OFF_SLOT + (size_t)T_TOK * NE * 4;
  constexpr size_t OFF_TG   = OFF_TIDX + (size_t)NE * CAPC * 4;
  constexpr size_t OFF_TSL  = OFF_TG + (size_t)NE * CAPC * 4;
  constexpr size_t OFF_CNT  = OFF_TSL + (size_t)NE * CAPC * 4;
  constexpr size_t OFF_YD   = ((OFF_CNT + NE * 4) + 255) & ~(size_t)255;
  constexpr size_t SZ_YD    = (size_t)T_TOK * KTOP * OD * 4;
  constexpr size_t OFF_H1   = OFF_YD + SZ_YD;
  constexpr size_t OFF_H2   = OFF_H1 + (size_t)NE * CAPC * HD * 2;
  constexpr size_t OFF_H3   = OFF_H2 + (size_t)NE * CAPC * HD * 2;
  constexpr size_t OFF_XBF  = OFF_H3 + (size_t)NE * CAPC * BTD * 2;
  constexpr size_t OFF_W2T  = ((OFF_XBF + (size_t)T_TOK * DIN * 2) + 255) & ~(size_t)255;
  constexpr size_t SZ_W2T   = (size_t)NE * (HD / 128) * (HD / 32) * 4096 * 2;   // 537 MB
  constexpr size_t OFF_W3T  = OFF_W2T + SZ_W2T;
  constexpr size_t SZ_W3T   = (size_t)NE * (BTD / 128) * (HD / 32) * 4096 * 2;  // 67 MB
  constexpr size_t OFF_WOT  = OFF_W3T + SZ_W3T;
  constexpr size_t SZ_WOT   = (size_t)NE * (OD / 128) * (BTD / 32) * 4096 * 2;  // 25 MB
  constexpr size_t NEED     = OFF_WOT + SZ_WOT;

  float* gate = (float*)(ws + OFF_GATE);
  int*   slot = (int*)(ws + OFF_SLOT);
  int*   tidx = (int*)(ws + OFF_TIDX);
  float* tg   = (float*)(ws + OFF_TG);
  int*   tsl  = (int*)(ws + OFF_TSL);
  int*   cnts = (int*)(ws + OFF_CNT);
  float* yd   = (float*)(ws + OFF_YD);
  unsigned short* h1  = (unsigned short*)(ws + OFF_H1);
  unsigned short* h2  = (unsigned short*)(ws + OFF_H2);
  unsigned short* h3  = (unsigned short*)(ws + OFF_H3);
  unsigned short* xbf = (unsigned short*)(ws + OFF_XBF);
  unsigned short* w2t = (unsigned short*)(ws + OFF_W2T);
  unsigned short* w3t = (unsigned short*)(ws + OFF_W3T);
  unsigned short* wot = (unsigned short*)(ws + OFF_WOT);

  hipMemsetAsync(yd, 0, SZ_YD, stream);
  cvt_x<<<T_TOK * DIN / 4 / 256, 256, 0, stream>>>(x, xbf);
  router_kernel<<<T_TOK / 8, 256, 0, stream>>>(x, noise, Wr, br, Wn, bn, gate, slot);
  dispatch_kernel<<<NE, 256, 0, stream>>>(gate, slot, tidx, tg, tsl, cnts);

  if (ws_size >= NEED) {
    // kernel A: GEMM1 (fp32 W1, r9 path) overlapped with dense retile of W2/W3/Wo
    fusedA<<<24576, 512, 0, stream>>>(xbf, W1, b1, h1, W2, w2t, W3, w3t, Wo, wot,
                                      tidx, tg, tsl, cnts);
    // G2..G4 on dense bf16 tiles, XCD-grouped, 2 blocks/CU
    moe_gemm_t2<HD, HD, false, 0, 16, 32><<<2048, 512, 0, stream>>>(
        h1, w2t, b2, h2, tidx, tg, tsl, cnts);
    moe_gemm_t2<HD, BTD, false, 1, 2, 4><<<256, 512, 0, stream>>>(
        h2, w3t, b3, h3, tidx, tg, tsl, cnts);
    moe_gemm_t2<BTD, OD, false, 2, 6, 12><<<768, 512, 0, stream>>>(
        h3, wot, bo, yd, tidx, tg, tsl, cnts);
  } else {
    // fallback: full r9 strided-fp32 path
    moe_gemm_big<DIN, HD, true, 0, 16, 32><<<2048, 512, 0, stream>>>(
        xbf, W1, b1, h1, tidx, tg, tsl, cnts);
    moe_gemm_big<HD, HD, false, 0, 16, 32><<<2048, 512, 0, stream>>>(
        h1, W2, b2, h2, tidx, tg, tsl, cnts);
    moe_gemm_big<HD, BTD, false, 1, 2, 8><<<512, 512, 0, stream>>>(
        h2, W3, b3, h3, tidx, tg, tsl, cnts);
    moe_gemm_big<BTD, OD, false, 2, 6, 24><<<1536, 512, 0, stream>>>(
        h3, Wo, bo, yd, tidx, tg, tsl, cnts);
  }
  combine_ln<<<T_TOK, 256, 0, stream>>>(yd, lw, lb, out);
}

// Round 12
// 845.719 us; speedup vs baseline: 1.3685x; 1.3231x over previous
//
#include <hip/hip_runtime.h>
#include <math.h>

#define T_TOK 2048
#define NE 64
#define KTOP 8
#define CAPC 512
#define DIN 768
#define HD 2048
#define BTD 256
#define OD 768

typedef short bf16x8 __attribute__((ext_vector_type(8)));
typedef float f32x4 __attribute__((ext_vector_type(4)));

__device__ __forceinline__ unsigned short f2bf(float f) {
  unsigned u = __float_as_uint(f);
  u += 0x7FFF + ((u >> 16) & 1);   // round-to-nearest-even
  return (unsigned short)(u >> 16);
}
__device__ __forceinline__ unsigned cvt2(float a, float b) {
  unsigned r;
  asm("v_cvt_pk_bf16_f32 %0, %1, %2" : "=v"(r) : "v"(a), "v"(b));
  return r;   // lo = bf16(a), hi = bf16(b)
}
__device__ __forceinline__ float gelu_exact(float v) {
  return 0.5f * v * (1.0f + erff(v * 0.7071067811865476f));
}
__device__ __forceinline__ void glds16(unsigned short* lds, const unsigned short* g) {
  __builtin_amdgcn_global_load_lds(
      (const __attribute__((address_space(1))) void*)g,
      (__attribute__((address_space(3))) void*)lds, 16, 0, 0);
}

// ---------------- x fp32 -> bf16 ---------------------------------------------------
__global__ __launch_bounds__(256) void cvt_x(const float* __restrict__ x,
                                             unsigned short* __restrict__ xb) {
  int i = blockIdx.x * 256 + threadIdx.x;
  float4 v = ((const float4*)x)[i];
  ushort4 o;
  o.x = f2bf(v.x); o.y = f2bf(v.y); o.z = f2bf(v.z); o.w = f2bf(v.w);
  ((ushort4*)xb)[i] = o;
}

// ---------------- router: fp32 logits, noisy top-8, softmax, gate/slot matrices ----
__global__ __launch_bounds__(256) void router_kernel(
    const float* __restrict__ x, const float* __restrict__ noise,
    const float* __restrict__ Wr, const float* __restrict__ br,
    const float* __restrict__ Wn, const float* __restrict__ bn,
    float* __restrict__ gate, int* __restrict__ slotm)
{
  __shared__ float xs[8][DIN];
  __shared__ float wrs[64][NE];
  __shared__ float wns[64][NE];
  const int tid = threadIdx.x;
  const int t0 = blockIdx.x * 8;
  for (int i = tid; i < 8 * (DIN / 4); i += 256) {
    int tt = i / (DIN / 4), c = i % (DIN / 4);
    ((float4*)xs[tt])[c] = ((const float4*)(x + (size_t)(t0 + tt) * DIN))[c];
  }
  const int lane = tid & 63;
  const int wv = tid >> 6;
  const int e = lane;
  const int ta = 2 * wv, tb = ta + 1;
  float ar0 = br[e], ar1 = ar0, an0 = bn[e], an1 = an0;
  for (int d0 = 0; d0 < DIN; d0 += 64) {
    __syncthreads();
    for (int i = tid; i < 64 * NE / 4; i += 256) {
      int dd = i >> 4, c4 = (i & 15) * 4;
      *(float4*)&wrs[dd][c4] = *(const float4*)&Wr[(size_t)(d0 + dd) * NE + c4];
      *(float4*)&wns[dd][c4] = *(const float4*)&Wn[(size_t)(d0 + dd) * NE + c4];
    }
    __syncthreads();
    #pragma unroll 8
    for (int dd = 0; dd < 64; dd++) {
      float wr = wrs[dd][e], wn = wns[dd][e];
      float xa = xs[ta][d0 + dd], xb = xs[tb][d0 + dd];
      ar0 = fmaf(xa, wr, ar0); ar1 = fmaf(xb, wr, ar1);
      an0 = fmaf(xa, wn, an0); an1 = fmaf(xb, wn, an1);
    }
  }
  #pragma unroll
  for (int s = 0; s < 2; s++) {
    int t = t0 + ta + s;
    float lr = s ? ar1 : ar0;
    float lnv = s ? an1 : an0;
    float sp = fmaxf(lnv, 0.f) + log1pf(expf(-fabsf(lnv)));   // softplus, overflow-safe
    float v = lr + noise[(size_t)t * NE + e] * sp;
    float cur = v;
    float topv[KTOP]; int topi[KTOP];
    #pragma unroll
    for (int j = 0; j < KTOP; j++) {
      float bv = cur; int bi = e;
      #pragma unroll
      for (int off = 32; off > 0; off >>= 1) {
        float ov = __shfl_xor(bv, off);
        int   oi = __shfl_xor(bi, off);
        if (ov > bv || (ov == bv && oi < bi)) { bv = ov; bi = oi; }
      }
      topv[j] = bv; topi[j] = bi;
      if (e == bi) cur = -INFINITY;
    }
    float mx = topv[0], se = 0.f, pv[KTOP];
    #pragma unroll
    for (int j = 0; j < KTOP; j++) { pv[j] = expf(topv[j] - mx); se += pv[j]; }
    float inv = 1.f / se;
    float g = 0.f; int sl = -1;
    #pragma unroll
    for (int j = 0; j < KTOP; j++) if (topi[j] == e) { g = pv[j] * inv; sl = j; }
    gate[(size_t)t * NE + e] = (sl >= 0) ? g : 0.f;
    slotm[(size_t)t * NE + e] = sl;
  }
}

// ---------------- dispatch: stable per-expert compaction (== stable argsort) -------
__global__ __launch_bounds__(256) void dispatch_kernel(
    const float* __restrict__ gate, const int* __restrict__ slotm,
    int* __restrict__ tok_idx, float* __restrict__ tok_g,
    int* __restrict__ tok_slot, int* __restrict__ counts)
{
  const int e = blockIdx.x;
  const int tid = threadIdx.x;
  __shared__ int wave_off[4];
  int base = 0;
  for (int t0 = 0; t0 < T_TOK; t0 += 256) {
    int t = t0 + tid;
    float g = gate[(size_t)t * NE + e];
    bool p = g > 0.f;
    unsigned long long m = __ballot(p);
    int wv = tid >> 6, lane = tid & 63;
    int pre = __popcll(m & ((1ull << lane) - 1ull));
    if (lane == 0) wave_off[wv] = __popcll(m);
    __syncthreads();
    int off = 0;
    for (int w = 0; w < wv; w++) off += wave_off[w];
    int tot = wave_off[0] + wave_off[1] + wave_off[2] + wave_off[3];
    if (p) {
      int pos = base + off + pre;
      if (pos < CAPC) {
        tok_idx[(size_t)e * CAPC + pos] = t;
        tok_g[(size_t)e * CAPC + pos] = g;
        tok_slot[(size_t)e * CAPC + pos] = slotm[(size_t)t * NE + e];
      }
    }
    base += tot;
    __syncthreads();
  }
  if (tid == 0) counts[e] = min(base, CAPC);
}

// ============== BM=320 expert GEMM: 320x128x32, role-split, XCD-grouped ============
// One m-tile covers cnt<=320 (~98% of experts) -> B panel fetched ONCE per expert.
// Waves 0-3 stage fp32 B (reg pipeline depth-3, vmcnt(16)); waves 4-7 stage bf16 A
// via 5 glds16/thread (depth-2, vmcnt(5)). All 8 waves compute 80x64 sub-tiles.
// LDS: A 3x20KB + B 2x10KB = 80KB, 1 block/CU (256-VGPR budget, no spill).
template<int KD, int NDT, bool AGATHER, int EPI, int NBN, int BPE>
__global__ __launch_bounds__(512, 1) void moe_gemm320(
    const unsigned short* __restrict__ Abf, const float* __restrict__ Bw,
    const float* __restrict__ bias, void* __restrict__ Outp,
    const int* __restrict__ tok_idx, const float* __restrict__ tok_g,
    const int* __restrict__ tok_slot, const int* __restrict__ counts)
{
  constexpr int NK = KD / 32;
  static_assert(NK % 4 == 0 && NK >= 8, "NK must be multiple of 4");
  const int bid = blockIdx.x;
  const int xcd = bid & 7;
  const int q   = bid >> 3;
  const int e     = (q / BPE) * 8 + xcd;
  const int inner = q % BPE;
  const int n0 = (inner % NBN) * 128;
  const int m0 = (inner / NBN) * 320;
  const int cnt = counts[e];
  if (m0 >= cnt) return;
  const int tid = threadIdx.x;
  const int lane = tid & 63, wave = tid >> 6;

  __shared__ unsigned short AL[3][320][32];   // 60 KB
  __shared__ unsigned short BL[2][128][40];   // 20 KB

  const bool isB = wave < 4;
  const int  w4  = wave & 3;

  // ---- B staging (waves 0-3): lane covers cols n0+2*lane..+1, k rows 8*w4..+7 ----
  const float* bp = Bw + (size_t)e * KD * NDT + (size_t)(8 * w4) * NDT + n0 + 2 * lane;
  float2 breg[4][8];

  // ---- A staging (waves 4-7): 5 glds16/thread, chunk-permuted source ----
  size_t a_off[5];
  if (!isB) {
    #pragma unroll
    for (int qq = 0; qq < 5; qq++) {
      int r  = w4 * 80 + qq * 16 + (lane >> 2);
      int cq = ((lane & 3) - (r >> 1)) & 3;
      size_t rowb;
      if (AGATHER) {
        int gr = min(m0 + r, CAPC - 1);
        int tk = (gr < cnt) ? tok_idx[(size_t)e * CAPC + gr] : 0;
        rowb = (size_t)tk * KD;
      } else {
        int gr = min(m0 + r, CAPC - 1);
        rowb = ((size_t)e * CAPC + gr) * KD;
      }
      a_off[qq] = rowb + 8 * cq;
    }
  }

  auto stageA = [&](int t, unsigned short* Abuf) {
    #pragma unroll
    for (int qq = 0; qq < 5; qq++)
      glds16(Abuf + w4 * 2560 + qq * 512, Abf + a_off[qq] + (size_t)t * 32);
  };
  auto loadB = [&](int t, int p) {
    const float* pb = bp + (size_t)t * 32 * NDT;
    #pragma unroll
    for (int j = 0; j < 8; j++) breg[p][j] = *(const float2*)(pb + (size_t)j * NDT);
  };
  auto writeB = [&](unsigned short* Bbuf, int p) {
    uint4 rx, ry;
    rx.x = cvt2(breg[p][0].x, breg[p][1].x); rx.y = cvt2(breg[p][2].x, breg[p][3].x);
    rx.z = cvt2(breg[p][4].x, breg[p][5].x); rx.w = cvt2(breg[p][6].x, breg[p][7].x);
    ry.x = cvt2(breg[p][0].y, breg[p][1].y); ry.y = cvt2(breg[p][2].y, breg[p][3].y);
    ry.z = cvt2(breg[p][4].y, breg[p][5].y); ry.w = cvt2(breg[p][6].y, breg[p][7].y);
    *(uint4*)(Bbuf + (2 * lane) * 40 + 8 * w4)     = rx;
    *(uint4*)(Bbuf + (2 * lane + 1) * 40 + 8 * w4) = ry;
  };

  const int wm = (wave >> 1) * 80;
  const int wn = (wave & 1) * 64;
  const int li = lane & 15, lg = lane >> 4;
  const int kxa = 8 * ((lg + ((li >> 1) & 3)) & 3);

  f32x4 acc[5][4];
  #pragma unroll
  for (int i = 0; i < 5; i++)
    #pragma unroll
    for (int j = 0; j < 4; j++) acc[i][j] = (f32x4){0.f, 0.f, 0.f, 0.f};

  auto step = [&](const unsigned short* Abuf, const unsigned short* Bbuf) {
    bf16x8 afr[5], bfr[4];
    #pragma unroll
    for (int mi = 0; mi < 5; mi++)
      afr[mi] = *(const bf16x8*)(Abuf + (wm + mi * 16 + li) * 32 + kxa);
    #pragma unroll
    for (int ni = 0; ni < 4; ni++)
      bfr[ni] = *(const bf16x8*)(Bbuf + (wn + ni * 16 + li) * 40 + lg * 8);
    __builtin_amdgcn_s_setprio(1);
    #pragma unroll
    for (int mi = 0; mi < 5; mi++)
      #pragma unroll
      for (int ni = 0; ni < 4; ni++)
        acc[mi][ni] = __builtin_amdgcn_mfma_f32_16x16x32_bf16(afr[mi], bfr[ni], acc[mi][ni], 0, 0, 0);
    __builtin_amdgcn_s_setprio(0);
  };

  unsigned short *A0 = &AL[0][0][0], *A1 = &AL[1][0][0], *A2 = &AL[2][0][0];
  unsigned short *B0 = &BL[0][0][0], *B1 = &BL[1][0][0];

  // ---- prologue ----
  if (isB) {
    loadB(0, 0); loadB(1, 1); loadB(2, 2);                 // 24 vm out
    asm volatile("s_waitcnt vmcnt(16)" ::: "memory");      // loadB(0) retired
    writeB(B0, 0);
    asm volatile("s_waitcnt lgkmcnt(0)" ::: "memory");
  } else {
    stageA(0, A0); stageA(1, A1);                          // 10 vm out
    asm volatile("s_waitcnt vmcnt(5)" ::: "memory");       // stageA(0) landed
  }
  __builtin_amdgcn_s_barrier();

  // steady sub-iter j (slot p = j&3):
  //   B-waves: issue loadB(j+3); after step vmcnt(16) retires loadB(j+1) -> writeB B1
  //   A-waves: issue stageA(j+2 -> A2); after step vmcnt(5) retires stageA(j+1)
  //   barrier publishes tile j+1; rotate pointers.
  #define SUBITER(p)                                                        \
    do {                                                                    \
      const int jj = jb + (p);                                              \
      if (isB) loadB(min(jj + 3, NK - 1), ((p) + 3) & 3);                   \
      else     stageA(min(jj + 2, NK - 1), A2);                             \
      step(A0, B0);                                                         \
      if (isB) {                                                            \
        asm volatile("s_waitcnt vmcnt(16)" ::: "memory");                   \
        writeB(B1, ((p) + 1) & 3);                                          \
        asm volatile("s_waitcnt lgkmcnt(0)" ::: "memory");                  \
      } else {                                                              \
        asm volatile("s_waitcnt vmcnt(5)" ::: "memory");                    \
      }                                                                     \
      __builtin_amdgcn_s_barrier();                                         \
      unsigned short* ta = A0; A0 = A1; A1 = A2; A2 = ta;                   \
      unsigned short* tb = B0; B0 = B1; B1 = tb;                            \
    } while (0)

  for (int jb = 0; jb < NK; jb += 4) {
    SUBITER(0); SUBITER(1); SUBITER(2); SUBITER(3);
  }
  #undef SUBITER
  asm volatile("s_waitcnt vmcnt(0)" ::: "memory");   // drain gload_lds before WG exit

  // ---- epilogue (EPI 0: bias+gelu->bf16, EPI 1: bias->bf16) ----
  const float* bpb = bias + (size_t)e * NDT;
  #pragma unroll
  for (int mi = 0; mi < 5; mi++) {
    #pragma unroll
    for (int ni = 0; ni < 4; ni++) {
      const int ncol = n0 + wn + ni * 16 + li;
      const float bb = bpb[ncol];
      #pragma unroll
      for (int qq = 0; qq < 4; qq++) {
        const int r = wm + mi * 16 + lg * 4 + qq;
        const int gr = m0 + r;
        if (gr < cnt) {
          float v = acc[mi][ni][qq] + bb;
          if (EPI == 0) v = gelu_exact(v);
          ((unsigned short*)Outp)[((size_t)e * CAPC + gr) * NDT + ncol] = f2bf(v);
        }
      }
    }
  }
}

// ---------------- 128x128x32 expert GEMM (verified) + XCD decode, for G4 -----------
template<int KD, int ND, bool AGATHER, int EPI, int NBN, int BPE>
__global__ __launch_bounds__(256, 2) void moe_gemm(
    const unsigned short* __restrict__ Abf, const float* __restrict__ Bw,
    const float* __restrict__ bias, void* __restrict__ Outp,
    const int* __restrict__ tok_idx, const float* __restrict__ tok_g,
    const int* __restrict__ tok_slot, const int* __restrict__ counts)
{
  constexpr int NK = KD / 32;
  static_assert(NK % 4 == 0 && NK >= 8, "NK must be multiple of 4");
  const int bid = blockIdx.x;
  const int xcd = bid & 7;
  const int q   = bid >> 3;
  const int e     = (q / BPE) * 8 + xcd;
  const int inner = q % BPE;
  const int n0 = (inner % NBN) * 128;
  const int m0 = (inner / NBN) * 128;
  const int cnt = counts[e];
  if (m0 >= cnt) return;
  const int tid = threadIdx.x;

  __shared__ unsigned short AL[4][128][32];
  __shared__ unsigned short BL[4][128][40];
  __shared__ int   s_tok[128];
  __shared__ float s_g[128];
  __shared__ int   s_slot[128];

  if (EPI == 2 && tid < 128) {
    int gr = m0 + tid;
    if (gr < cnt) {
      s_tok[tid]  = tok_idx[(size_t)e * CAPC + gr];
      s_g[tid]    = tok_g[(size_t)e * CAPC + gr];
      s_slot[tid] = tok_slot[(size_t)e * CAPC + gr];
    }
  }

  const int ar0 = tid >> 2;
  const int ac  = 8 * (((tid & 3) - (tid >> 3)) & 3);
  size_t arow0, arow1;
  if (AGATHER) {
    int g0 = m0 + ar0, g1 = m0 + 64 + ar0;
    int t0i = (g0 < cnt) ? tok_idx[(size_t)e * CAPC + g0] : 0;
    int t1i = (g1 < cnt) ? tok_idx[(size_t)e * CAPC + g1] : 0;
    arow0 = (size_t)t0i * KD; arow1 = (size_t)t1i * KD;
  } else {
    arow0 = ((size_t)e * CAPC + m0 + ar0) * KD;
    arow1 = arow0 + (size_t)64 * KD;
  }
  const unsigned short* ap0 = Abf + arow0 + ac;
  const unsigned short* ap1 = Abf + arow1 + ac;
  const int awb = (tid & 192) * 8;

  const int l = tid & 63, w = tid >> 6;
  const float* bp = Bw + (size_t)e * KD * ND + (size_t)(8 * w) * ND + n0 + 2 * l;

  float2 breg[4][8];

  auto stageA = [&](int t, int s) {
    glds16(&AL[s][0][0] + awb,        ap0 + t * 32);
    glds16(&AL[s][0][0] + 2048 + awb, ap1 + t * 32);
  };
  auto loadB = [&](int t, int p) {
    const float* pb = bp + (size_t)t * 32 * ND;
    #pragma unroll
    for (int j = 0; j < 8; j++) breg[p][j] = *(const float2*)(pb + (size_t)j * ND);
  };
  auto writeB = [&](int s, int p) {
    uint4 rx, ry;
    rx.x = cvt2(breg[p][0].x, breg[p][1].x); rx.y = cvt2(breg[p][2].x, breg[p][3].x);
    rx.z = cvt2(breg[p][4].x, breg[p][5].x); rx.w = cvt2(breg[p][6].x, breg[p][7].x);
    ry.x = cvt2(breg[p][0].y, breg[p][1].y); ry.y = cvt2(breg[p][2].y, breg[p][3].y);
    ry.z = cvt2(breg[p][4].y, breg[p][5].y); ry.w = cvt2(breg[p][6].y, breg[p][7].y);
    *(uint4*)&BL[s][2 * l][8 * w]     = rx;
    *(uint4*)&BL[s][2 * l + 1][8 * w] = ry;
  };

  const int lane = tid & 63, wv = tid >> 6;
  const int wm = (wv >> 1) * 64, wn = (wv & 1) * 64;
  const int li = lane & 15, lg = lane >> 4;
  const int kxa = 8 * ((lg + ((li >> 1) & 3)) & 3);

  f32x4 acc[4][4];
  #pragma unroll
  for (int i = 0; i < 4; i++)
    #pragma unroll
    for (int j = 0; j < 4; j++) acc[i][j] = (f32x4){0.f, 0.f, 0.f, 0.f};

  auto step = [&](int s) {
    bf16x8 afr[4], bfr[4];
    #pragma unroll
    for (int mi = 0; mi < 4; mi++)
      afr[mi] = *(const bf16x8*)&AL[s][wm + mi * 16 + li][kxa];
    #pragma unroll
    for (int ni = 0; ni < 4; ni++)
      bfr[ni] = *(const bf16x8*)&BL[s][wn + ni * 16 + li][lg * 8];
    __builtin_amdgcn_s_setprio(1);
    #pragma unroll
    for (int mi = 0; mi < 4; mi++)
      #pragma unroll
      for (int ni = 0; ni < 4; ni++)
        acc[mi][ni] = __builtin_amdgcn_mfma_f32_16x16x32_bf16(afr[mi], bfr[ni], acc[mi][ni], 0, 0, 0);
    __builtin_amdgcn_s_setprio(0);
  };

  loadB(0, 0);
  stageA(0, 0); loadB(1, 1);
  stageA(1, 1); loadB(2, 2);
  stageA(2, 2); loadB(3, 3);
  asm volatile("s_waitcnt vmcnt(28)" ::: "memory");
  writeB(0, 0);
  asm volatile("s_waitcnt lgkmcnt(0)" ::: "memory");
  __builtin_amdgcn_s_barrier();

  #define SUBITER(p)                                                        \
    do {                                                                    \
      const int jj = jb + (p);                                              \
      stageA(min(jj + 3, NK - 1), ((p) + 3) & 3);                           \
      loadB(min(jj + 4, NK - 1), (p));                                      \
      step(p);                                                              \
      asm volatile("s_waitcnt vmcnt(28)" ::: "memory");                     \
      writeB(((p) + 1) & 3, ((p) + 1) & 3);                                 \
      asm volatile("s_waitcnt lgkmcnt(0)" ::: "memory");                    \
      __builtin_amdgcn_s_barrier();                                         \
    } while (0)

  for (int jb = 0; jb < NK; jb += 4) {
    SUBITER(0); SUBITER(1); SUBITER(2); SUBITER(3);
  }
  #undef SUBITER
  asm volatile("s_waitcnt vmcnt(0)" ::: "memory");

  const float* bpb = bias + (size_t)e * ND;
  #pragma unroll
  for (int mi = 0; mi < 4; mi++) {
    #pragma unroll
    for (int ni = 0; ni < 4; ni++) {
      const int ncol = n0 + wn + ni * 16 + li;
      const float bb = bpb[ncol];
      #pragma unroll
      for (int qq = 0; qq < 4; qq++) {
        const int r = wm + mi * 16 + lg * 4 + qq;
        const int gr = m0 + r;
        if (gr < cnt) {
          float v = acc[mi][ni][qq] + bb;
          if (EPI == 0) {
            v = gelu_exact(v);
            ((unsigned short*)Outp)[((size_t)e * CAPC + gr) * ND + ncol] = f2bf(v);
          } else if (EPI == 1) {
            ((unsigned short*)Outp)[((size_t)e * CAPC + gr) * ND + ncol] = f2bf(v);
          } else {
            ((float*)Outp)[((size_t)s_tok[r] * KTOP + s_slot[r]) * OD + ncol] = v * s_g[r];
          }
        }
      }
    }
  }
}

// ---------------- combine 8 slots + LayerNorm -------------------------------------
__global__ __launch_bounds__(256) void combine_ln(
    const float* __restrict__ yd, const float* __restrict__ lw,
    const float* __restrict__ lb, float* __restrict__ out)
{
  const int t = blockIdx.x, tid = threadIdx.x;
  float v[3];
  #pragma unroll
  for (int i = 0; i < 3; i++) {
    const int c = tid + 256 * i;
    float s = 0.f;
    #pragma unroll
    for (int j = 0; j < KTOP; j++) s += yd[((size_t)t * KTOP + j) * OD + c];
    v[i] = s;
  }
  float s1 = v[0] + v[1] + v[2];
  float s2 = v[0] * v[0] + v[1] * v[1] + v[2] * v[2];
  #pragma unroll
  for (int off = 32; off > 0; off >>= 1) {
    s1 += __shfl_xor(s1, off);
    s2 += __shfl_xor(s2, off);
  }
  __shared__ float as1[4], as2[4];
  const int lane = tid & 63, wv = tid >> 6;
  if (lane == 0) { as1[wv] = s1; as2[wv] = s2; }
  __syncthreads();
  s1 = as1[0] + as1[1] + as1[2] + as1[3];
  s2 = as2[0] + as2[1] + as2[2] + as2[3];
  const float mu = s1 * (1.f / OD);
  const float var = s2 * (1.f / OD) - mu * mu;
  const float rstd = rsqrtf(var + 1e-5f);
  #pragma unroll
  for (int i = 0; i < 3; i++) {
    const int c = tid + 256 * i;
    out[(size_t)t * OD + c] = (v[i] - mu) * rstd * lw[c] + lb[c];
  }
}

extern "C" void kernel_launch(void* const* d_in, const int* in_sizes, int n_in,
                              void* d_out, int out_size, void* d_ws, size_t ws_size,
                              hipStream_t stream) {
  const float* x     = (const float*)d_in[0];
  const float* noise = (const float*)d_in[1];
  const float* Wr    = (const float*)d_in[2];
  const float* br    = (const float*)d_in[3];
  const float* Wn    = (const float*)d_in[4];
  const float* bn    = (const float*)d_in[5];
  const float* W1    = (const float*)d_in[6];
  const float* b1    = (const float*)d_in[7];
  const float* W2    = (const float*)d_in[8];
  const float* b2    = (const float*)d_in[9];
  const float* W3    = (const float*)d_in[10];
  const float* b3    = (const float*)d_in[11];
  const float* Wo    = (const float*)d_in[12];
  const float* bo    = (const float*)d_in[13];
  const float* lw    = (const float*)d_in[14];
  const float* lb    = (const float*)d_in[15];
  float* out = (float*)d_out;

  char* ws = (char*)d_ws;
  constexpr size_t OFF_GATE = 0;
  constexpr size_t OFF_SLOT = OFF_GATE + (size_t)T_TOK * NE * 4;
  constexpr size_t OFF_TIDX = OFF_SLOT + (size_t)T_TOK * NE * 4;
  constexpr size_t OFF_TG   = OFF_TIDX + (size_t)NE * CAPC * 4;
  constexpr size_t OFF_TSL  = OFF_TG + (size_t)NE * CAPC * 4;
  constexpr size_t OFF_CNT  = OFF_TSL + (size_t)NE * CAPC * 4;
  constexpr size_t OFF_YD   = ((OFF_CNT + NE * 4) + 255) & ~(size_t)255;
  constexpr size_t SZ_YD    = (size_t)T_TOK * KTOP * OD * 4;
  constexpr size_t OFF_H1   = OFF_YD + SZ_YD;
  constexpr size_t OFF_H2   = OFF_H1 + (size_t)NE * CAPC * HD * 2;
  constexpr size_t OFF_H3   = OFF_H2 + (size_t)NE * CAPC * HD * 2;
  constexpr size_t OFF_XBF  = OFF_H3 + (size_t)NE * CAPC * BTD * 2;

  float* gate = (float*)(ws + OFF_GATE);
  int*   slot = (int*)(ws + OFF_SLOT);
  int*   tidx = (int*)(ws + OFF_TIDX);
  float* tg   = (float*)(ws + OFF_TG);
  int*   tsl  = (int*)(ws + OFF_TSL);
  int*   cnts = (int*)(ws + OFF_CNT);
  float* yd   = (float*)(ws + OFF_YD);
  unsigned short* h1  = (unsigned short*)(ws + OFF_H1);
  unsigned short* h2  = (unsigned short*)(ws + OFF_H2);
  unsigned short* h3  = (unsigned short*)(ws + OFF_H3);
  unsigned short* xbf = (unsigned short*)(ws + OFF_XBF);

  hipMemsetAsync(yd, 0, SZ_YD, stream);
  cvt_x<<<T_TOK * DIN / 4 / 256, 256, 0, stream>>>(x, xbf);
  router_kernel<<<T_TOK / 8, 256, 0, stream>>>(x, noise, Wr, br, Wn, bn, gate, slot);
  dispatch_kernel<<<NE, 256, 0, stream>>>(gate, slot, tidx, tg, tsl, cnts);
  // G1: 16 n-panels x 2 m(320) x 64 e -> BPE=32, XCD-grouped
  moe_gemm320<DIN, HD, true, 0, 16, 32><<<2048, 512, 0, stream>>>(
      xbf, W1, b1, h1, tidx, tg, tsl, cnts);
  // G2: same geometry
  moe_gemm320<HD, HD, false, 0, 16, 32><<<2048, 512, 0, stream>>>(
      h1, W2, b2, h2, tidx, tg, tsl, cnts);
  // G3: 2 n x 2 m(320) x 64 e -> BPE=4
  moe_gemm320<HD, BTD, false, 1, 2, 4><<<256, 512, 0, stream>>>(
      h2, W3, b3, h3, tidx, tg, tsl, cnts);
  // G4: 6 n x 4 m(128) x 64 e -> BPE=24 (verified 128-tile kernel, scatter epilogue)
  moe_gemm<BTD, OD, false, 2, 6, 24><<<1536, 256, 0, stream>>>(
      h3, Wo, bo, yd, tidx, tg, tsl, cnts);
  combine_ln<<<T_TOK, 256, 0, stream>>>(yd, lw, lb, out);
}

// Round 13
// 814.171 us; speedup vs baseline: 1.4215x; 1.0387x over previous
//
#include <hip/hip_runtime.h>
#include <math.h>

#define T_TOK 2048
#define NE 64
#define KTOP 8
#define CAPC 512
#define DIN 768
#define HD 2048
#define BTD 256
#define OD 768

typedef short bf16x8 __attribute__((ext_vector_type(8)));
typedef float f32x4 __attribute__((ext_vector_type(4)));

__device__ __forceinline__ unsigned short f2bf(float f) {
  unsigned u = __float_as_uint(f);
  u += 0x7FFF + ((u >> 16) & 1);   // round-to-nearest-even
  return (unsigned short)(u >> 16);
}
__device__ __forceinline__ unsigned cvt2(float a, float b) {
  unsigned r;
  asm("v_cvt_pk_bf16_f32 %0, %1, %2" : "=v"(r) : "v"(a), "v"(b));
  return r;   // lo = bf16(a), hi = bf16(b)
}
__device__ __forceinline__ float gelu_exact(float v) {
  return 0.5f * v * (1.0f + erff(v * 0.7071067811865476f));
}
__device__ __forceinline__ void glds16(unsigned short* lds, const unsigned short* g) {
  __builtin_amdgcn_global_load_lds(
      (const __attribute__((address_space(1))) void*)g,
      (__attribute__((address_space(3))) void*)lds, 16, 0, 0);
}

// ---------------- x fp32 -> bf16 ---------------------------------------------------
__global__ __launch_bounds__(256) void cvt_x(const float* __restrict__ x,
                                             unsigned short* __restrict__ xb) {
  int i = blockIdx.x * 256 + threadIdx.x;
  float4 v = ((const float4*)x)[i];
  ushort4 o;
  o.x = f2bf(v.x); o.y = f2bf(v.y); o.z = f2bf(v.z); o.w = f2bf(v.w);
  ((ushort4*)xb)[i] = o;
}

// ---------------- router: fp32 logits, noisy top-8, softmax, gate/slot matrices ----
__global__ __launch_bounds__(256) void router_kernel(
    const float* __restrict__ x, const float* __restrict__ noise,
    const float* __restrict__ Wr, const float* __restrict__ br,
    const float* __restrict__ Wn, const float* __restrict__ bn,
    float* __restrict__ gate, int* __restrict__ slotm)
{
  __shared__ float xs[8][DIN];
  __shared__ float wrs[64][NE];
  __shared__ float wns[64][NE];
  const int tid = threadIdx.x;
  const int t0 = blockIdx.x * 8;
  for (int i = tid; i < 8 * (DIN / 4); i += 256) {
    int tt = i / (DIN / 4), c = i % (DIN / 4);
    ((float4*)xs[tt])[c] = ((const float4*)(x + (size_t)(t0 + tt) * DIN))[c];
  }
  const int lane = tid & 63;
  const int wv = tid >> 6;
  const int e = lane;
  const int ta = 2 * wv, tb = ta + 1;
  float ar0 = br[e], ar1 = ar0, an0 = bn[e], an1 = an0;
  for (int d0 = 0; d0 < DIN; d0 += 64) {
    __syncthreads();
    for (int i = tid; i < 64 * NE / 4; i += 256) {
      int dd = i >> 4, c4 = (i & 15) * 4;
      *(float4*)&wrs[dd][c4] = *(const float4*)&Wr[(size_t)(d0 + dd) * NE + c4];
      *(float4*)&wns[dd][c4] = *(const float4*)&Wn[(size_t)(d0 + dd) * NE + c4];
    }
    __syncthreads();
    #pragma unroll 8
    for (int dd = 0; dd < 64; dd++) {
      float wr = wrs[dd][e], wn = wns[dd][e];
      float xa = xs[ta][d0 + dd], xb = xs[tb][d0 + dd];
      ar0 = fmaf(xa, wr, ar0); ar1 = fmaf(xb, wr, ar1);
      an0 = fmaf(xa, wn, an0); an1 = fmaf(xb, wn, an1);
    }
  }
  #pragma unroll
  for (int s = 0; s < 2; s++) {
    int t = t0 + ta + s;
    float lr = s ? ar1 : ar0;
    float lnv = s ? an1 : an0;
    float sp = fmaxf(lnv, 0.f) + log1pf(expf(-fabsf(lnv)));   // softplus, overflow-safe
    float v = lr + noise[(size_t)t * NE + e] * sp;
    float cur = v;
    float topv[KTOP]; int topi[KTOP];
    #pragma unroll
    for (int j = 0; j < KTOP; j++) {
      float bv = cur; int bi = e;
      #pragma unroll
      for (int off = 32; off > 0; off >>= 1) {
        float ov = __shfl_xor(bv, off);
        int   oi = __shfl_xor(bi, off);
        if (ov > bv || (ov == bv && oi < bi)) { bv = ov; bi = oi; }
      }
      topv[j] = bv; topi[j] = bi;
      if (e == bi) cur = -INFINITY;
    }
    float mx = topv[0], se = 0.f, pv[KTOP];
    #pragma unroll
    for (int j = 0; j < KTOP; j++) { pv[j] = expf(topv[j] - mx); se += pv[j]; }
    float inv = 1.f / se;
    float g = 0.f; int sl = -1;
    #pragma unroll
    for (int j = 0; j < KTOP; j++) if (topi[j] == e) { g = pv[j] * inv; sl = j; }
    gate[(size_t)t * NE + e] = (sl >= 0) ? g : 0.f;
    slotm[(size_t)t * NE + e] = sl;
  }
}

// ---------------- dispatch: stable per-expert compaction (== stable argsort) -------
__global__ __launch_bounds__(256) void dispatch_kernel(
    const float* __restrict__ gate, const int* __restrict__ slotm,
    int* __restrict__ tok_idx, float* __restrict__ tok_g,
    int* __restrict__ tok_slot, int* __restrict__ counts)
{
  const int e = blockIdx.x;
  const int tid = threadIdx.x;
  __shared__ int wave_off[4];
  int base = 0;
  for (int t0 = 0; t0 < T_TOK; t0 += 256) {
    int t = t0 + tid;
    float g = gate[(size_t)t * NE + e];
    bool p = g > 0.f;
    unsigned long long m = __ballot(p);
    int wv = tid >> 6, lane = tid & 63;
    int pre = __popcll(m & ((1ull << lane) - 1ull));
    if (lane == 0) wave_off[wv] = __popcll(m);
    __syncthreads();
    int off = 0;
    for (int w = 0; w < wv; w++) off += wave_off[w];
    int tot = wave_off[0] + wave_off[1] + wave_off[2] + wave_off[3];
    if (p) {
      int pos = base + off + pre;
      if (pos < CAPC) {
        tok_idx[(size_t)e * CAPC + pos] = t;
        tok_g[(size_t)e * CAPC + pos] = g;
        tok_slot[(size_t)e * CAPC + pos] = slotm[(size_t)t * NE + e];
      }
    }
    base += tot;
    __syncthreads();
  }
  if (tid == 0) counts[e] = min(base, CAPC);
}

// ============== BM=320 expert GEMM, optional K-split, role-split, XCD-grouped ======
// Waves 0-3 stage fp32 B (depth-3, vmcnt(16), chunk-XOR-swizzled LDS writes: 4-way
// instead of 16-way bank conflict); waves 4-7 stage bf16 A via 5 glds16 (depth-2,
// vmcnt(5)). 8 waves compute 80x64 sub-tiles. LDS 80KB, 1 block/CU.
// EPI: 0 bias+gelu->bf16; 1 bias->bf16; 3 fp32 partial (no bias) to Outp[ksp]
template<int KD, int NDT, bool AGATHER, int EPI, int NBN, int BPE, int KSPL>
__global__ __launch_bounds__(512, 1) void moe_gemm320(
    const unsigned short* __restrict__ Abf, const float* __restrict__ Bw,
    const float* __restrict__ bias, void* __restrict__ Outp,
    const int* __restrict__ tok_idx, const float* __restrict__ tok_g,
    const int* __restrict__ tok_slot, const int* __restrict__ counts)
{
  constexpr int NKT = KD / 32;
  constexpr int NKL = NKT / KSPL;
  static_assert(NKL % 4 == 0 && NKL >= 8, "NKL must be multiple of 4");
  const int bid = blockIdx.x;
  const int xcd = bid & 7;
  const int q   = bid >> 3;
  const int e     = (q / BPE) * 8 + xcd;
  const int inner = q % BPE;
  const int n0  = (inner % NBN) * 128;
  const int ksp = (inner / NBN) % KSPL;
  const int m0  = (inner / (NBN * KSPL)) * 320;
  const int kbase = ksp * (KD / KSPL);
  const int cnt = counts[e];
  if (m0 >= cnt) return;
  const int tid = threadIdx.x;
  const int lane = tid & 63, wave = tid >> 6;

  __shared__ unsigned short AL[3][320][32];   // 60 KB
  __shared__ unsigned short BL[2][128][40];   // 20 KB

  const bool isB = wave < 4;
  const int  w4  = wave & 3;

  // ---- B staging (waves 0-3): lane covers cols n0+2*lane..+1, k rows 8*w4..+7 ----
  const float* bp = Bw + (size_t)e * KD * NDT + (size_t)(kbase + 8 * w4) * NDT + n0 + 2 * lane;
  float2 breg[4][8];
  const int bxs = 8 * (w4 ^ ((lane >> 2) & 3));   // chunk-XOR swizzle slot

  // ---- A staging (waves 4-7): 5 glds16/thread, chunk-permuted source ----
  size_t a_off[5];
  if (!isB) {
    #pragma unroll
    for (int qq = 0; qq < 5; qq++) {
      int r  = w4 * 80 + qq * 16 + (lane >> 2);
      int cq = ((lane & 3) - (r >> 1)) & 3;
      size_t rowb;
      int gr = min(m0 + r, CAPC - 1);
      if (AGATHER) {
        int tk = (gr < cnt) ? tok_idx[(size_t)e * CAPC + gr] : 0;
        rowb = (size_t)tk * KD;
      } else {
        rowb = ((size_t)e * CAPC + gr) * KD;
      }
      a_off[qq] = rowb + kbase + 8 * cq;
    }
  }

  auto stageA = [&](int t, unsigned short* Abuf) {
    #pragma unroll
    for (int qq = 0; qq < 5; qq++)
      glds16(Abuf + w4 * 2560 + qq * 512, Abf + a_off[qq] + (size_t)t * 32);
  };
  auto loadB = [&](int t, int p) {
    const float* pb = bp + (size_t)t * 32 * NDT;
    #pragma unroll
    for (int j = 0; j < 8; j++) breg[p][j] = *(const float2*)(pb + (size_t)j * NDT);
  };
  auto writeB = [&](unsigned short* Bbuf, int p) {
    uint4 rx, ry;
    rx.x = cvt2(breg[p][0].x, breg[p][1].x); rx.y = cvt2(breg[p][2].x, breg[p][3].x);
    rx.z = cvt2(breg[p][4].x, breg[p][5].x); rx.w = cvt2(breg[p][6].x, breg[p][7].x);
    ry.x = cvt2(breg[p][0].y, breg[p][1].y); ry.y = cvt2(breg[p][2].y, breg[p][3].y);
    ry.z = cvt2(breg[p][4].y, breg[p][5].y); ry.w = cvt2(breg[p][6].y, breg[p][7].y);
    *(uint4*)(Bbuf + (2 * lane) * 40 + bxs)     = rx;
    *(uint4*)(Bbuf + (2 * lane + 1) * 40 + bxs) = ry;
  };

  const int wm = (wave >> 1) * 80;
  const int wn = (wave & 1) * 64;
  const int li = lane & 15, lg = lane >> 4;
  const int kxa = 8 * ((lg + ((li >> 1) & 3)) & 3);
  int kxb[4];
  #pragma unroll
  for (int ni = 0; ni < 4; ni++) {
    int row = wn + ni * 16 + li;
    kxb[ni] = row * 40 + 8 * (lg ^ ((row >> 3) & 3));
  }

  f32x4 acc[5][4];
  #pragma unroll
  for (int i = 0; i < 5; i++)
    #pragma unroll
    for (int j = 0; j < 4; j++) acc[i][j] = (f32x4){0.f, 0.f, 0.f, 0.f};

  auto step = [&](const unsigned short* Abuf, const unsigned short* Bbuf) {
    bf16x8 afr[5], bfr[4];
    #pragma unroll
    for (int mi = 0; mi < 5; mi++)
      afr[mi] = *(const bf16x8*)(Abuf + (wm + mi * 16 + li) * 32 + kxa);
    #pragma unroll
    for (int ni = 0; ni < 4; ni++)
      bfr[ni] = *(const bf16x8*)(Bbuf + kxb[ni]);
    __builtin_amdgcn_s_setprio(1);
    #pragma unroll
    for (int mi = 0; mi < 5; mi++)
      #pragma unroll
      for (int ni = 0; ni < 4; ni++)
        acc[mi][ni] = __builtin_amdgcn_mfma_f32_16x16x32_bf16(afr[mi], bfr[ni], acc[mi][ni], 0, 0, 0);
    __builtin_amdgcn_s_setprio(0);
  };

  unsigned short *A0 = &AL[0][0][0], *A1 = &AL[1][0][0], *A2 = &AL[2][0][0];
  unsigned short *B0 = &BL[0][0][0], *B1 = &BL[1][0][0];

  // ---- prologue ----
  if (isB) {
    loadB(0, 0); loadB(1, 1); loadB(2, 2);                 // 24 vm out
    asm volatile("s_waitcnt vmcnt(16)" ::: "memory");      // loadB(0) retired
    writeB(B0, 0);
    asm volatile("s_waitcnt lgkmcnt(0)" ::: "memory");
  } else {
    stageA(0, A0); stageA(1, A1);                          // 10 vm out
    asm volatile("s_waitcnt vmcnt(5)" ::: "memory");       // stageA(0) landed
  }
  __builtin_amdgcn_s_barrier();

  #define SUBITER(p)                                                        \
    do {                                                                    \
      const int jj = jb + (p);                                              \
      if (isB) loadB(min(jj + 3, NKL - 1), ((p) + 3) & 3);                  \
      else     stageA(min(jj + 2, NKL - 1), A2);                            \
      step(A0, B0);                                                         \
      if (isB) {                                                            \
        asm volatile("s_waitcnt vmcnt(16)" ::: "memory");                   \
        writeB(B1, ((p) + 1) & 3);                                          \
        asm volatile("s_waitcnt lgkmcnt(0)" ::: "memory");                  \
      } else {                                                              \
        asm volatile("s_waitcnt vmcnt(5)" ::: "memory");                    \
      }                                                                     \
      __builtin_amdgcn_s_barrier();                                         \
      unsigned short* ta = A0; A0 = A1; A1 = A2; A2 = ta;                   \
      unsigned short* tb = B0; B0 = B1; B1 = tb;                            \
    } while (0)

  for (int jb = 0; jb < NKL; jb += 4) {
    SUBITER(0); SUBITER(1); SUBITER(2); SUBITER(3);
  }
  #undef SUBITER
  asm volatile("s_waitcnt vmcnt(0)" ::: "memory");   // drain gload_lds before WG exit

  // ---- epilogue ----
  const float* bpb = bias + (size_t)e * NDT;
  #pragma unroll
  for (int mi = 0; mi < 5; mi++) {
    #pragma unroll
    for (int ni = 0; ni < 4; ni++) {
      const int ncol = n0 + wn + ni * 16 + li;
      const float bb = (EPI == 3) ? 0.f : bpb[ncol];
      #pragma unroll
      for (int qq = 0; qq < 4; qq++) {
        const int r = wm + mi * 16 + lg * 4 + qq;
        const int gr = m0 + r;
        if (gr < cnt) {
          float v = acc[mi][ni][qq] + bb;
          if (EPI == 0) {
            v = gelu_exact(v);
            ((unsigned short*)Outp)[((size_t)e * CAPC + gr) * NDT + ncol] = f2bf(v);
          } else if (EPI == 1) {
            ((unsigned short*)Outp)[((size_t)e * CAPC + gr) * NDT + ncol] = f2bf(v);
          } else {
            ((float*)Outp)[((size_t)ksp * NE * CAPC + (size_t)e * CAPC + gr) * NDT + ncol] = v;
          }
        }
      }
    }
  }
}

// ---------------- h3 = cvt(partial0 + partial1 + bias) -----------------------------
__global__ __launch_bounds__(256) void h3sum(const float* __restrict__ p,
                                             const float* __restrict__ b3,
                                             unsigned short* __restrict__ h3) {
  constexpr size_t SEG = (size_t)NE * CAPC * BTD;
  size_t i = (size_t)blockIdx.x * 1024 + (size_t)threadIdx.x * 4;
  float4 a = *(const float4*)(p + i);
  float4 b = *(const float4*)(p + SEG + i);
  int c = (int)(i % BTD);
  int e = (int)(i / ((size_t)CAPC * BTD));
  const float* bb = b3 + (size_t)e * BTD + c;
  ushort4 o;
  o.x = f2bf(a.x + b.x + bb[0]); o.y = f2bf(a.y + b.y + bb[1]);
  o.z = f2bf(a.z + b.z + bb[2]); o.w = f2bf(a.w + b.w + bb[3]);
  *(ushort4*)(h3 + i) = o;
}

// ---------------- 128x128x32 expert GEMM + XCD decode, for G4 (bf16 yd scatter) ----
template<int KD, int ND, bool AGATHER, int EPI, int NBN, int BPE>
__global__ __launch_bounds__(256, 2) void moe_gemm(
    const unsigned short* __restrict__ Abf, const float* __restrict__ Bw,
    const float* __restrict__ bias, void* __restrict__ Outp,
    const int* __restrict__ tok_idx, const float* __restrict__ tok_g,
    const int* __restrict__ tok_slot, const int* __restrict__ counts)
{
  constexpr int NK = KD / 32;
  static_assert(NK % 4 == 0 && NK >= 8, "NK must be multiple of 4");
  const int bid = blockIdx.x;
  const int xcd = bid & 7;
  const int q   = bid >> 3;
  const int e     = (q / BPE) * 8 + xcd;
  const int inner = q % BPE;
  const int n0 = (inner % NBN) * 128;
  const int m0 = (inner / NBN) * 128;
  const int cnt = counts[e];
  if (m0 >= cnt) return;
  const int tid = threadIdx.x;

  __shared__ unsigned short AL[4][128][32];
  __shared__ unsigned short BL[4][128][40];
  __shared__ int   s_tok[128];
  __shared__ float s_g[128];
  __shared__ int   s_slot[128];

  if (EPI == 2 && tid < 128) {
    int gr = m0 + tid;
    if (gr < cnt) {
      s_tok[tid]  = tok_idx[(size_t)e * CAPC + gr];
      s_g[tid]    = tok_g[(size_t)e * CAPC + gr];
      s_slot[tid] = tok_slot[(size_t)e * CAPC + gr];
    }
  }

  const int ar0 = tid >> 2;
  const int ac  = 8 * (((tid & 3) - (tid >> 3)) & 3);
  size_t arow0, arow1;
  if (AGATHER) {
    int g0 = m0 + ar0, g1 = m0 + 64 + ar0;
    int t0i = (g0 < cnt) ? tok_idx[(size_t)e * CAPC + g0] : 0;
    int t1i = (g1 < cnt) ? tok_idx[(size_t)e * CAPC + g1] : 0;
    arow0 = (size_t)t0i * KD; arow1 = (size_t)t1i * KD;
  } else {
    arow0 = ((size_t)e * CAPC + m0 + ar0) * KD;
    arow1 = arow0 + (size_t)64 * KD;
  }
  const unsigned short* ap0 = Abf + arow0 + ac;
  const unsigned short* ap1 = Abf + arow1 + ac;
  const int awb = (tid & 192) * 8;

  const int l = tid & 63, w = tid >> 6;
  const float* bp = Bw + (size_t)e * KD * ND + (size_t)(8 * w) * ND + n0 + 2 * l;

  float2 breg[4][8];

  auto stageA = [&](int t, int s) {
    glds16(&AL[s][0][0] + awb,        ap0 + t * 32);
    glds16(&AL[s][0][0] + 2048 + awb, ap1 + t * 32);
  };
  auto loadB = [&](int t, int p) {
    const float* pb = bp + (size_t)t * 32 * ND;
    #pragma unroll
    for (int j = 0; j < 8; j++) breg[p][j] = *(const float2*)(pb + (size_t)j * ND);
  };
  auto writeB = [&](int s, int p) {
    uint4 rx, ry;
    rx.x = cvt2(breg[p][0].x, breg[p][1].x); rx.y = cvt2(breg[p][2].x, breg[p][3].x);
    rx.z = cvt2(breg[p][4].x, breg[p][5].x); rx.w = cvt2(breg[p][6].x, breg[p][7].x);
    ry.x = cvt2(breg[p][0].y, breg[p][1].y); ry.y = cvt2(breg[p][2].y, breg[p][3].y);
    ry.z = cvt2(breg[p][4].y, breg[p][5].y); ry.w = cvt2(breg[p][6].y, breg[p][7].y);
    *(uint4*)&BL[s][2 * l][8 * w]     = rx;
    *(uint4*)&BL[s][2 * l + 1][8 * w] = ry;
  };

  const int lane = tid & 63, wv = tid >> 6;
  const int wm = (wv >> 1) * 64, wn = (wv & 1) * 64;
  const int li = lane & 15, lg = lane >> 4;
  const int kxa = 8 * ((lg + ((li >> 1) & 3)) & 3);

  f32x4 acc[4][4];
  #pragma unroll
  for (int i = 0; i < 4; i++)
    #pragma unroll
    for (int j = 0; j < 4; j++) acc[i][j] = (f32x4){0.f, 0.f, 0.f, 0.f};

  auto step = [&](int s) {
    bf16x8 afr[4], bfr[4];
    #pragma unroll
    for (int mi = 0; mi < 4; mi++)
      afr[mi] = *(const bf16x8*)&AL[s][wm + mi * 16 + li][kxa];
    #pragma unroll
    for (int ni = 0; ni < 4; ni++)
      bfr[ni] = *(const bf16x8*)&BL[s][wn + ni * 16 + li][lg * 8];
    __builtin_amdgcn_s_setprio(1);
    #pragma unroll
    for (int mi = 0; mi < 4; mi++)
      #pragma unroll
      for (int ni = 0; ni < 4; ni++)
        acc[mi][ni] = __builtin_amdgcn_mfma_f32_16x16x32_bf16(afr[mi], bfr[ni], acc[mi][ni], 0, 0, 0);
    __builtin_amdgcn_s_setprio(0);
  };

  loadB(0, 0);
  stageA(0, 0); loadB(1, 1);
  stageA(1, 1); loadB(2, 2);
  stageA(2, 2); loadB(3, 3);
  asm volatile("s_waitcnt vmcnt(28)" ::: "memory");
  writeB(0, 0);
  asm volatile("s_waitcnt lgkmcnt(0)" ::: "memory");
  __builtin_amdgcn_s_barrier();

  #define SUBITER(p)                                                        \
    do {                                                                    \
      const int jj = jb + (p);                                              \
      stageA(min(jj + 3, NK - 1), ((p) + 3) & 3);                           \
      loadB(min(jj + 4, NK - 1), (p));                                      \
      step(p);                                                              \
      asm volatile("s_waitcnt vmcnt(28)" ::: "memory");                     \
      writeB(((p) + 1) & 3, ((p) + 1) & 3);                                 \
      asm volatile("s_waitcnt lgkmcnt(0)" ::: "memory");                    \
      __builtin_amdgcn_s_barrier();                                         \
    } while (0)

  for (int jb = 0; jb < NK; jb += 4) {
    SUBITER(0); SUBITER(1); SUBITER(2); SUBITER(3);
  }
  #undef SUBITER
  asm volatile("s_waitcnt vmcnt(0)" ::: "memory");

  const float* bpb = bias + (size_t)e * ND;
  #pragma unroll
  for (int mi = 0; mi < 4; mi++) {
    #pragma unroll
    for (int ni = 0; ni < 4; ni++) {
      const int ncol = n0 + wn + ni * 16 + li;
      const float bb = bpb[ncol];
      #pragma unroll
      for (int qq = 0; qq < 4; qq++) {
        const int r = wm + mi * 16 + lg * 4 + qq;
        const int gr = m0 + r;
        if (gr < cnt) {
          float v = acc[mi][ni][qq] + bb;
          if (EPI == 0) {
            v = gelu_exact(v);
            ((unsigned short*)Outp)[((size_t)e * CAPC + gr) * ND + ncol] = f2bf(v);
          } else if (EPI == 1) {
            ((unsigned short*)Outp)[((size_t)e * CAPC + gr) * ND + ncol] = f2bf(v);
          } else {
            ((unsigned short*)Outp)[((size_t)s_tok[r] * KTOP + s_slot[r]) * OD + ncol]
                = f2bf(v * s_g[r]);
          }
        }
      }
    }
  }
}

// ---------------- combine 8 bf16 slots + LayerNorm ---------------------------------
__global__ __launch_bounds__(256) void combine_ln(
    const unsigned short* __restrict__ yd, const float* __restrict__ lw,
    const float* __restrict__ lb, float* __restrict__ out)
{
  const int t = blockIdx.x, tid = threadIdx.x;
  float v[3];
  #pragma unroll
  for (int i = 0; i < 3; i++) {
    const int c = tid + 256 * i;
    float s = 0.f;
    #pragma unroll
    for (int j = 0; j < KTOP; j++) {
      unsigned u = yd[((size_t)t * KTOP + j) * OD + c];
      s += __uint_as_float(u << 16);
    }
    v[i] = s;
  }
  float s1 = v[0] + v[1] + v[2];
  float s2 = v[0] * v[0] + v[1] * v[1] + v[2] * v[2];
  #pragma unroll
  for (int off = 32; off > 0; off >>= 1) {
    s1 += __shfl_xor(s1, off);
    s2 += __shfl_xor(s2, off);
  }
  __shared__ float as1[4], as2[4];
  const int lane = tid & 63, wv = tid >> 6;
  if (lane == 0) { as1[wv] = s1; as2[wv] = s2; }
  __syncthreads();
  s1 = as1[0] + as1[1] + as1[2] + as1[3];
  s2 = as2[0] + as2[1] + as2[2] + as2[3];
  const float mu = s1 * (1.f / OD);
  const float var = s2 * (1.f / OD) - mu * mu;
  const float rstd = rsqrtf(var + 1e-5f);
  #pragma unroll
  for (int i = 0; i < 3; i++) {
    const int c = tid + 256 * i;
    out[(size_t)t * OD + c] = (v[i] - mu) * rstd * lw[c] + lb[c];
  }
}

extern "C" void kernel_launch(void* const* d_in, const int* in_sizes, int n_in,
                              void* d_out, int out_size, void* d_ws, size_t ws_size,
                              hipStream_t stream) {
  const float* x     = (const float*)d_in[0];
  const float* noise = (const float*)d_in[1];
  const float* Wr    = (const float*)d_in[2];
  const float* br    = (const float*)d_in[3];
  const float* Wn    = (const float*)d_in[4];
  const float* bn    = (const float*)d_in[5];
  const float* W1    = (const float*)d_in[6];
  const float* b1    = (const float*)d_in[7];
  const float* W2    = (const float*)d_in[8];
  const float* b2    = (const float*)d_in[9];
  const float* W3    = (const float*)d_in[10];
  const float* b3    = (const float*)d_in[11];
  const float* Wo    = (const float*)d_in[12];
  const float* bo    = (const float*)d_in[13];
  const float* lw    = (const float*)d_in[14];
  const float* lb    = (const float*)d_in[15];
  float* out = (float*)d_out;

  char* ws = (char*)d_ws;
  constexpr size_t OFF_GATE = 0;
  constexpr size_t OFF_SLOT = OFF_GATE + (size_t)T_TOK * NE * 4;
  constexpr size_t OFF_TIDX = OFF_SLOT + (size_t)T_TOK * NE * 4;
  constexpr size_t OFF_TG   = OFF_TIDX + (size_t)NE * CAPC * 4;
  constexpr size_t OFF_TSL  = OFF_TG + (size_t)NE * CAPC * 4;
  constexpr size_t OFF_CNT  = OFF_TSL + (size_t)NE * CAPC * 4;
  constexpr size_t OFF_YD   = ((OFF_CNT + NE * 4) + 255) & ~(size_t)255;
  constexpr size_t SZ_YD    = (size_t)T_TOK * KTOP * OD * 2;     // bf16 now
  constexpr size_t OFF_H1   = ((OFF_YD + SZ_YD) + 255) & ~(size_t)255;
  constexpr size_t OFF_H2   = OFF_H1 + (size_t)NE * CAPC * HD * 2;
  constexpr size_t OFF_H3   = OFF_H2 + (size_t)NE * CAPC * HD * 2;
  constexpr size_t OFF_XBF  = OFF_H3 + (size_t)NE * CAPC * BTD * 2;
  constexpr size_t OFF_H3P  = ((OFF_XBF + (size_t)T_TOK * DIN * 2) + 255) & ~(size_t)255;

  float* gate = (float*)(ws + OFF_GATE);
  int*   slot = (int*)(ws + OFF_SLOT);
  int*   tidx = (int*)(ws + OFF_TIDX);
  float* tg   = (float*)(ws + OFF_TG);
  int*   tsl  = (int*)(ws + OFF_TSL);
  int*   cnts = (int*)(ws + OFF_CNT);
  unsigned short* yd  = (unsigned short*)(ws + OFF_YD);
  unsigned short* h1  = (unsigned short*)(ws + OFF_H1);
  unsigned short* h2  = (unsigned short*)(ws + OFF_H2);
  unsigned short* h3  = (unsigned short*)(ws + OFF_H3);
  unsigned short* xbf = (unsigned short*)(ws + OFF_XBF);
  float* h3p = (float*)(ws + OFF_H3P);

  hipMemsetAsync(yd, 0, SZ_YD, stream);
  cvt_x<<<T_TOK * DIN / 4 / 256, 256, 0, stream>>>(x, xbf);
  router_kernel<<<T_TOK / 8, 256, 0, stream>>>(x, noise, Wr, br, Wn, bn, gate, slot);
  dispatch_kernel<<<NE, 256, 0, stream>>>(gate, slot, tidx, tg, tsl, cnts);
  // G1: 16 n x 2 m(320) x 64 e, XCD-grouped
  moe_gemm320<DIN, HD, true, 0, 16, 32, 1><<<2048, 512, 0, stream>>>(
      xbf, W1, b1, h1, tidx, tg, tsl, cnts);
  // G2: same geometry
  moe_gemm320<HD, HD, false, 0, 16, 32, 1><<<2048, 512, 0, stream>>>(
      h1, W2, b2, h2, tidx, tg, tsl, cnts);
  // G3: K-split 2 -> fp32 partials; 2 n x 2 ksp x 2 m(320) x 64 e
  moe_gemm320<HD, BTD, false, 3, 2, 8, 2><<<512, 512, 0, stream>>>(
      h2, W3, b3, h3p, tidx, tg, tsl, cnts);
  h3sum<<<(NE * CAPC * BTD) / 1024, 256, 0, stream>>>(h3p, b3, h3);
  // G4: 6 n x 4 m(128) x 64 e, bf16 yd scatter
  moe_gemm<BTD, OD, false, 2, 6, 24><<<1536, 256, 0, stream>>>(
      h3, Wo, bo, yd, tidx, tg, tsl, cnts);
  combine_ln<<<T_TOK, 256, 0, stream>>>(yd, lw, lb, out);
}

// Round 14
// 808.561 us; speedup vs baseline: 1.4314x; 1.0069x over previous
//
#include <hip/hip_runtime.h>
#include <math.h>

#define T_TOK 2048
#define NE 64
#define KTOP 8
#define CAPC 512
#define DIN 768
#define HD 2048
#define BTD 256
#define OD 768

typedef short bf16x8 __attribute__((ext_vector_type(8)));
typedef float f32x4 __attribute__((ext_vector_type(4)));

__device__ __forceinline__ unsigned short f2bf(float f) {
  unsigned u = __float_as_uint(f);
  u += 0x7FFF + ((u >> 16) & 1);   // round-to-nearest-even
  return (unsigned short)(u >> 16);
}
__device__ __forceinline__ unsigned cvt2(float a, float b) {
  unsigned r;
  asm("v_cvt_pk_bf16_f32 %0, %1, %2" : "=v"(r) : "v"(a), "v"(b));
  return r;   // lo = bf16(a), hi = bf16(b)
}
__device__ __forceinline__ float gelu_exact(float v) {
  return 0.5f * v * (1.0f + erff(v * 0.7071067811865476f));
}
__device__ __forceinline__ void glds16(unsigned short* lds, const unsigned short* g) {
  __builtin_amdgcn_global_load_lds(
      (const __attribute__((address_space(1))) void*)g,
      (__attribute__((address_space(3))) void*)lds, 16, 0, 0);
}

// ---------------- router (+ fused x->bf16 conversion) ------------------------------
__global__ __launch_bounds__(256) void router_kernel(
    const float* __restrict__ x, const float* __restrict__ noise,
    const float* __restrict__ Wr, const float* __restrict__ br,
    const float* __restrict__ Wn, const float* __restrict__ bn,
    float* __restrict__ gate, int* __restrict__ slotm,
    unsigned short* __restrict__ xbf)
{
  __shared__ float xs[8][DIN];
  __shared__ float wrs[64][NE];
  __shared__ float wns[64][NE];
  const int tid = threadIdx.x;
  const int t0 = blockIdx.x * 8;
  for (int i = tid; i < 8 * (DIN / 4); i += 256) {
    int tt = i / (DIN / 4), c = i % (DIN / 4);
    float4 v = ((const float4*)(x + (size_t)(t0 + tt) * DIN))[c];
    ((float4*)xs[tt])[c] = v;
    ushort4 o;
    o.x = f2bf(v.x); o.y = f2bf(v.y); o.z = f2bf(v.z); o.w = f2bf(v.w);
    ((ushort4*)(xbf + (size_t)(t0 + tt) * DIN))[c] = o;
  }
  const int lane = tid & 63;
  const int wv = tid >> 6;
  const int e = lane;
  const int ta = 2 * wv, tb = ta + 1;
  float ar0 = br[e], ar1 = ar0, an0 = bn[e], an1 = an0;
  for (int d0 = 0; d0 < DIN; d0 += 64) {
    __syncthreads();
    for (int i = tid; i < 64 * NE / 4; i += 256) {
      int dd = i >> 4, c4 = (i & 15) * 4;
      *(float4*)&wrs[dd][c4] = *(const float4*)&Wr[(size_t)(d0 + dd) * NE + c4];
      *(float4*)&wns[dd][c4] = *(const float4*)&Wn[(size_t)(d0 + dd) * NE + c4];
    }
    __syncthreads();
    #pragma unroll 8
    for (int dd = 0; dd < 64; dd++) {
      float wr = wrs[dd][e], wn = wns[dd][e];
      float xa = xs[ta][d0 + dd], xb = xs[tb][d0 + dd];
      ar0 = fmaf(xa, wr, ar0); ar1 = fmaf(xb, wr, ar1);
      an0 = fmaf(xa, wn, an0); an1 = fmaf(xb, wn, an1);
    }
  }
  #pragma unroll
  for (int s = 0; s < 2; s++) {
    int t = t0 + ta + s;
    float lr = s ? ar1 : ar0;
    float lnv = s ? an1 : an0;
    float sp = fmaxf(lnv, 0.f) + log1pf(expf(-fabsf(lnv)));   // softplus, overflow-safe
    float v = lr + noise[(size_t)t * NE + e] * sp;
    float cur = v;
    float topv[KTOP]; int topi[KTOP];
    #pragma unroll
    for (int j = 0; j < KTOP; j++) {
      float bv = cur; int bi = e;
      #pragma unroll
      for (int off = 32; off > 0; off >>= 1) {
        float ov = __shfl_xor(bv, off);
        int   oi = __shfl_xor(bi, off);
        if (ov > bv || (ov == bv && oi < bi)) { bv = ov; bi = oi; }
      }
      topv[j] = bv; topi[j] = bi;
      if (e == bi) cur = -INFINITY;
    }
    float mx = topv[0], se = 0.f, pv[KTOP];
    #pragma unroll
    for (int j = 0; j < KTOP; j++) { pv[j] = expf(topv[j] - mx); se += pv[j]; }
    float inv = 1.f / se;
    float g = 0.f; int sl = -1;
    #pragma unroll
    for (int j = 0; j < KTOP; j++) if (topi[j] == e) { g = pv[j] * inv; sl = j; }
    gate[(size_t)t * NE + e] = (sl >= 0) ? g : 0.f;
    slotm[(size_t)t * NE + e] = sl;
  }
}

// ---------------- dispatch: stable per-expert compaction (== stable argsort) -------
__global__ __launch_bounds__(256) void dispatch_kernel(
    const float* __restrict__ gate, const int* __restrict__ slotm,
    int* __restrict__ tok_idx, float* __restrict__ tok_g,
    int* __restrict__ tok_slot, int* __restrict__ counts)
{
  const int e = blockIdx.x;
  const int tid = threadIdx.x;
  __shared__ int wave_off[4];
  int base = 0;
  for (int t0 = 0; t0 < T_TOK; t0 += 256) {
    int t = t0 + tid;
    float g = gate[(size_t)t * NE + e];
    bool p = g > 0.f;
    unsigned long long m = __ballot(p);
    int wv = tid >> 6, lane = tid & 63;
    int pre = __popcll(m & ((1ull << lane) - 1ull));
    if (lane == 0) wave_off[wv] = __popcll(m);
    __syncthreads();
    int off = 0;
    for (int w = 0; w < wv; w++) off += wave_off[w];
    int tot = wave_off[0] + wave_off[1] + wave_off[2] + wave_off[3];
    if (p) {
      int pos = base + off + pre;
      if (pos < CAPC) {
        tok_idx[(size_t)e * CAPC + pos] = t;
        tok_g[(size_t)e * CAPC + pos] = g;
        tok_slot[(size_t)e * CAPC + pos] = slotm[(size_t)t * NE + e];
      }
    }
    base += tot;
    __syncthreads();
  }
  if (tid == 0) counts[e] = min(base, CAPC);
}

// ============== BM=320 expert GEMM, optional K-split, role-split, XCD-grouped ======
// Waves 0-3 stage fp32 B (depth-3, vmcnt(16), chunk-XOR-swizzled LDS writes);
// waves 4-7 stage bf16 A via 5 glds16 (depth-2, vmcnt(5)). 8 waves compute 80x64.
// EPI: 0 bias+gelu->bf16; 1 bias->bf16; 2 (bias+v)*g bf16 scatter; 3 fp32 partial
template<int KD, int NDT, bool AGATHER, int EPI, int NBN, int BPE, int KSPL>
__global__ __launch_bounds__(512, 1) void moe_gemm320(
    const unsigned short* __restrict__ Abf, const float* __restrict__ Bw,
    const float* __restrict__ bias, void* __restrict__ Outp,
    const int* __restrict__ tok_idx, const float* __restrict__ tok_g,
    const int* __restrict__ tok_slot, const int* __restrict__ counts)
{
  constexpr int NKT = KD / 32;
  constexpr int NKL = NKT / KSPL;
  static_assert(NKL % 4 == 0 && NKL >= 8, "NKL must be multiple of 4");
  const int bid = blockIdx.x;
  const int xcd = bid & 7;
  const int q   = bid >> 3;
  const int e     = (q / BPE) * 8 + xcd;
  const int inner = q % BPE;
  const int n0  = (inner % NBN) * 128;
  const int ksp = (inner / NBN) % KSPL;
  const int m0  = (inner / (NBN * KSPL)) * 320;
  const int kbase = ksp * (KD / KSPL);
  const int cnt = counts[e];
  if (m0 >= cnt) return;
  const int tid = threadIdx.x;
  const int lane = tid & 63, wave = tid >> 6;

  __shared__ unsigned short AL[3][320][32];   // 60 KB
  __shared__ unsigned short BL[2][128][40];   // 20 KB
  __shared__ int   s_tok[EPI == 2 ? 320 : 1];
  __shared__ float s_g[EPI == 2 ? 320 : 1];
  __shared__ int   s_slot[EPI == 2 ? 320 : 1];

  if (EPI == 2 && tid < 320) {
    int gr = m0 + tid;
    if (gr < cnt) {
      s_tok[tid]  = tok_idx[(size_t)e * CAPC + gr];
      s_g[tid]    = tok_g[(size_t)e * CAPC + gr];
      s_slot[tid] = tok_slot[(size_t)e * CAPC + gr];
    }
  }

  const bool isB = wave < 4;
  const int  w4  = wave & 3;

  // ---- B staging (waves 0-3): lane covers cols n0+2*lane..+1, k rows 8*w4..+7 ----
  const float* bp = Bw + (size_t)e * KD * NDT + (size_t)(kbase + 8 * w4) * NDT + n0 + 2 * lane;
  float2 breg[4][8];
  const int bxs = 8 * (w4 ^ ((lane >> 2) & 3));   // chunk-XOR swizzle slot

  // ---- A staging (waves 4-7): 5 glds16/thread, chunk-permuted source ----
  size_t a_off[5];
  if (!isB) {
    #pragma unroll
    for (int qq = 0; qq < 5; qq++) {
      int r  = w4 * 80 + qq * 16 + (lane >> 2);
      int cq = ((lane & 3) - (r >> 1)) & 3;
      size_t rowb;
      int gr = min(m0 + r, CAPC - 1);
      if (AGATHER) {
        int tk = (gr < cnt) ? tok_idx[(size_t)e * CAPC + gr] : 0;
        rowb = (size_t)tk * KD;
      } else {
        rowb = ((size_t)e * CAPC + gr) * KD;
      }
      a_off[qq] = rowb + kbase + 8 * cq;
    }
  }

  auto stageA = [&](int t, unsigned short* Abuf) {
    #pragma unroll
    for (int qq = 0; qq < 5; qq++)
      glds16(Abuf + w4 * 2560 + qq * 512, Abf + a_off[qq] + (size_t)t * 32);
  };
  auto loadB = [&](int t, int p) {
    const float* pb = bp + (size_t)t * 32 * NDT;
    #pragma unroll
    for (int j = 0; j < 8; j++) breg[p][j] = *(const float2*)(pb + (size_t)j * NDT);
  };
  auto writeB = [&](unsigned short* Bbuf, int p) {
    uint4 rx, ry;
    rx.x = cvt2(breg[p][0].x, breg[p][1].x); rx.y = cvt2(breg[p][2].x, breg[p][3].x);
    rx.z = cvt2(breg[p][4].x, breg[p][5].x); rx.w = cvt2(breg[p][6].x, breg[p][7].x);
    ry.x = cvt2(breg[p][0].y, breg[p][1].y); ry.y = cvt2(breg[p][2].y, breg[p][3].y);
    ry.z = cvt2(breg[p][4].y, breg[p][5].y); ry.w = cvt2(breg[p][6].y, breg[p][7].y);
    *(uint4*)(Bbuf + (2 * lane) * 40 + bxs)     = rx;
    *(uint4*)(Bbuf + (2 * lane + 1) * 40 + bxs) = ry;
  };

  const int wm = (wave >> 1) * 80;
  const int wn = (wave & 1) * 64;
  const int li = lane & 15, lg = lane >> 4;
  const int kxa = 8 * ((lg + ((li >> 1) & 3)) & 3);
  int kxb[4];
  #pragma unroll
  for (int ni = 0; ni < 4; ni++) {
    int row = wn + ni * 16 + li;
    kxb[ni] = row * 40 + 8 * (lg ^ ((row >> 3) & 3));
  }

  f32x4 acc[5][4];
  #pragma unroll
  for (int i = 0; i < 5; i++)
    #pragma unroll
    for (int j = 0; j < 4; j++) acc[i][j] = (f32x4){0.f, 0.f, 0.f, 0.f};

  auto step = [&](const unsigned short* Abuf, const unsigned short* Bbuf) {
    bf16x8 afr[5], bfr[4];
    #pragma unroll
    for (int mi = 0; mi < 5; mi++)
      afr[mi] = *(const bf16x8*)(Abuf + (wm + mi * 16 + li) * 32 + kxa);
    #pragma unroll
    for (int ni = 0; ni < 4; ni++)
      bfr[ni] = *(const bf16x8*)(Bbuf + kxb[ni]);
    __builtin_amdgcn_s_setprio(1);
    #pragma unroll
    for (int mi = 0; mi < 5; mi++)
      #pragma unroll
      for (int ni = 0; ni < 4; ni++)
        acc[mi][ni] = __builtin_amdgcn_mfma_f32_16x16x32_bf16(afr[mi], bfr[ni], acc[mi][ni], 0, 0, 0);
    __builtin_amdgcn_s_setprio(0);
  };

  unsigned short *A0 = &AL[0][0][0], *A1 = &AL[1][0][0], *A2 = &AL[2][0][0];
  unsigned short *B0 = &BL[0][0][0], *B1 = &BL[1][0][0];

  // ---- prologue ----
  if (isB) {
    loadB(0, 0); loadB(1, 1); loadB(2, 2);                 // 24 vm out
    asm volatile("s_waitcnt vmcnt(16)" ::: "memory");      // loadB(0) retired
    writeB(B0, 0);
    asm volatile("s_waitcnt lgkmcnt(0)" ::: "memory");
  } else {
    stageA(0, A0); stageA(1, A1);                          // 10 vm out
    asm volatile("s_waitcnt vmcnt(5)" ::: "memory");       // stageA(0) landed
  }
  __builtin_amdgcn_s_barrier();

  #define SUBITER(p)                                                        \
    do {                                                                    \
      const int jj = jb + (p);                                              \
      if (isB) loadB(min(jj + 3, NKL - 1), ((p) + 3) & 3);                  \
      else     stageA(min(jj + 2, NKL - 1), A2);                            \
      step(A0, B0);                                                         \
      if (isB) {                                                            \
        asm volatile("s_waitcnt vmcnt(16)" ::: "memory");                   \
        writeB(B1, ((p) + 1) & 3);                                          \
        asm volatile("s_waitcnt lgkmcnt(0)" ::: "memory");                  \
      } else {                                                              \
        asm volatile("s_waitcnt vmcnt(5)" ::: "memory");                    \
      }                                                                     \
      __builtin_amdgcn_s_barrier();                                         \
      unsigned short* ta = A0; A0 = A1; A1 = A2; A2 = ta;                   \
      unsigned short* tb = B0; B0 = B1; B1 = tb;                            \
    } while (0)

  for (int jb = 0; jb < NKL; jb += 4) {
    SUBITER(0); SUBITER(1); SUBITER(2); SUBITER(3);
  }
  #undef SUBITER
  asm volatile("s_waitcnt vmcnt(0)" ::: "memory");   // drain gload_lds before WG exit

  // ---- epilogue ----
  const float* bpb = bias + (size_t)e * NDT;
  #pragma unroll
  for (int mi = 0; mi < 5; mi++) {
    #pragma unroll
    for (int ni = 0; ni < 4; ni++) {
      const int ncol = n0 + wn + ni * 16 + li;
      const float bb = (EPI == 3) ? 0.f : bpb[ncol];
      #pragma unroll
      for (int qq = 0; qq < 4; qq++) {
        const int r = wm + mi * 16 + lg * 4 + qq;
        const int gr = m0 + r;
        if (gr < cnt) {
          float v = acc[mi][ni][qq] + bb;
          if (EPI == 0) {
            v = gelu_exact(v);
            ((unsigned short*)Outp)[((size_t)e * CAPC + gr) * NDT + ncol] = f2bf(v);
          } else if (EPI == 1) {
            ((unsigned short*)Outp)[((size_t)e * CAPC + gr) * NDT + ncol] = f2bf(v);
          } else if (EPI == 2) {
            ((unsigned short*)Outp)[((size_t)s_tok[r] * KTOP + s_slot[r]) * OD + ncol]
                = f2bf(v * s_g[r]);
          } else {
            ((float*)Outp)[((size_t)ksp * NE * CAPC + (size_t)e * CAPC + gr) * NDT + ncol] = v;
          }
        }
      }
    }
  }
}

// ---------------- h3 = cvt(partial0 + partial1 + bias) -----------------------------
__global__ __launch_bounds__(256) void h3sum(const float* __restrict__ p,
                                             const float* __restrict__ b3,
                                             unsigned short* __restrict__ h3) {
  constexpr size_t SEG = (size_t)NE * CAPC * BTD;
  size_t i = (size_t)blockIdx.x * 1024 + (size_t)threadIdx.x * 4;
  float4 a = *(const float4*)(p + i);
  float4 b = *(const float4*)(p + SEG + i);
  int c = (int)(i % BTD);
  int e = (int)(i / ((size_t)CAPC * BTD));
  const float* bb = b3 + (size_t)e * BTD + c;
  ushort4 o;
  o.x = f2bf(a.x + b.x + bb[0]); o.y = f2bf(a.y + b.y + bb[1]);
  o.z = f2bf(a.z + b.z + bb[2]); o.w = f2bf(a.w + b.w + bb[3]);
  *(ushort4*)(h3 + i) = o;
}

// ---------------- combine 8 bf16 slots + LayerNorm ---------------------------------
__global__ __launch_bounds__(256) void combine_ln(
    const unsigned short* __restrict__ yd, const float* __restrict__ lw,
    const float* __restrict__ lb, float* __restrict__ out)
{
  const int t = blockIdx.x, tid = threadIdx.x;
  float v[3];
  #pragma unroll
  for (int i = 0; i < 3; i++) {
    const int c = tid + 256 * i;
    float s = 0.f;
    #pragma unroll
    for (int j = 0; j < KTOP; j++) {
      unsigned u = yd[((size_t)t * KTOP + j) * OD + c];
      s += __uint_as_float(u << 16);
    }
    v[i] = s;
  }
  float s1 = v[0] + v[1] + v[2];
  float s2 = v[0] * v[0] + v[1] * v[1] + v[2] * v[2];
  #pragma unroll
  for (int off = 32; off > 0; off >>= 1) {
    s1 += __shfl_xor(s1, off);
    s2 += __shfl_xor(s2, off);
  }
  __shared__ float as1[4], as2[4];
  const int lane = tid & 63, wv = tid >> 6;
  if (lane == 0) { as1[wv] = s1; as2[wv] = s2; }
  __syncthreads();
  s1 = as1[0] + as1[1] + as1[2] + as1[3];
  s2 = as2[0] + as2[1] + as2[2] + as2[3];
  const float mu = s1 * (1.f / OD);
  const float var = s2 * (1.f / OD) - mu * mu;
  const float rstd = rsqrtf(var + 1e-5f);
  #pragma unroll
  for (int i = 0; i < 3; i++) {
    const int c = tid + 256 * i;
    out[(size_t)t * OD + c] = (v[i] - mu) * rstd * lw[c] + lb[c];
  }
}

extern "C" void kernel_launch(void* const* d_in, const int* in_sizes, int n_in,
                              void* d_out, int out_size, void* d_ws, size_t ws_size,
                              hipStream_t stream) {
  const float* x     = (const float*)d_in[0];
  const float* noise = (const float*)d_in[1];
  const float* Wr    = (const float*)d_in[2];
  const float* br    = (const float*)d_in[3];
  const float* Wn    = (const float*)d_in[4];
  const float* bn    = (const float*)d_in[5];
  const float* W1    = (const float*)d_in[6];
  const float* b1    = (const float*)d_in[7];
  const float* W2    = (const float*)d_in[8];
  const float* b2    = (const float*)d_in[9];
  const float* W3    = (const float*)d_in[10];
  const float* b3    = (const float*)d_in[11];
  const float* Wo    = (const float*)d_in[12];
  const float* bo    = (const float*)d_in[13];
  const float* lw    = (const float*)d_in[14];
  const float* lb    = (const float*)d_in[15];
  float* out = (float*)d_out;

  char* ws = (char*)d_ws;
  constexpr size_t OFF_GATE = 0;
  constexpr size_t OFF_SLOT = OFF_GATE + (size_t)T_TOK * NE * 4;
  constexpr size_t OFF_TIDX = OFF_SLOT + (size_t)T_TOK * NE * 4;
  constexpr size_t OFF_TG   = OFF_TIDX + (size_t)NE * CAPC * 4;
  constexpr size_t OFF_TSL  = OFF_TG + (size_t)NE * CAPC * 4;
  constexpr size_t OFF_CNT  = OFF_TSL + (size_t)NE * CAPC * 4;
  constexpr size_t OFF_YD   = ((OFF_CNT + NE * 4) + 255) & ~(size_t)255;
  constexpr size_t SZ_YD    = (size_t)T_TOK * KTOP * OD * 2;     // bf16
  constexpr size_t OFF_H1   = ((OFF_YD + SZ_YD) + 255) & ~(size_t)255;
  constexpr size_t OFF_H2   = OFF_H1 + (size_t)NE * CAPC * HD * 2;
  constexpr size_t OFF_H3   = OFF_H2 + (size_t)NE * CAPC * HD * 2;
  constexpr size_t OFF_XBF  = OFF_H3 + (size_t)NE * CAPC * BTD * 2;
  constexpr size_t OFF_H3P  = ((OFF_XBF + (size_t)T_TOK * DIN * 2) + 255) & ~(size_t)255;

  float* gate = (float*)(ws + OFF_GATE);
  int*   slot = (int*)(ws + OFF_SLOT);
  int*   tidx = (int*)(ws + OFF_TIDX);
  float* tg   = (float*)(ws + OFF_TG);
  int*   tsl  = (int*)(ws + OFF_TSL);
  int*   cnts = (int*)(ws + OFF_CNT);
  unsigned short* yd  = (unsigned short*)(ws + OFF_YD);
  unsigned short* h1  = (unsigned short*)(ws + OFF_H1);
  unsigned short* h2  = (unsigned short*)(ws + OFF_H2);
  unsigned short* h3  = (unsigned short*)(ws + OFF_H3);
  unsigned short* xbf = (unsigned short*)(ws + OFF_XBF);
  float* h3p = (float*)(ws + OFF_H3P);

  hipMemsetAsync(yd, 0, SZ_YD, stream);
  router_kernel<<<T_TOK / 8, 256, 0, stream>>>(x, noise, Wr, br, Wn, bn, gate, slot, xbf);
  dispatch_kernel<<<NE, 256, 0, stream>>>(gate, slot, tidx, tg, tsl, cnts);
  // G1: 16 n x 2 m(320) x 64 e, XCD-grouped
  moe_gemm320<DIN, HD, true, 0, 16, 32, 1><<<2048, 512, 0, stream>>>(
      xbf, W1, b1, h1, tidx, tg, tsl, cnts);
  // G2: same geometry
  moe_gemm320<HD, HD, false, 0, 16, 32, 1><<<2048, 512, 0, stream>>>(
      h1, W2, b2, h2, tidx, tg, tsl, cnts);
  // G3: K-split 2 -> fp32 partials; 2 n x 2 ksp x 2 m(320) x 64 e
  moe_gemm320<HD, BTD, false, 3, 2, 8, 2><<<512, 512, 0, stream>>>(
      h2, W3, b3, h3p, tidx, tg, tsl, cnts);
  h3sum<<<(NE * CAPC * BTD) / 1024, 256, 0, stream>>>(h3p, b3, h3);
  // G4: 6 n x 1 m(320) x 64 e -> Wo fetched once; bf16 yd scatter
  moe_gemm320<BTD, OD, false, 2, 6, 6, 1><<<384, 512, 0, stream>>>(
      h3, Wo, bo, yd, tidx, tg, tsl, cnts);
  combine_ln<<<T_TOK, 256, 0, stream>>>(yd, lw, lb, out);
}